// Round 6
// baseline (664.851 us; speedup 1.0000x reference)
//
#include <hip/hip_runtime.h>
#include <hip/hip_bf16.h>

typedef __hip_bfloat16 bf16;
typedef __attribute__((ext_vector_type(8))) short bf16x8;  // 8 bf16 in 4 VGPRs
typedef __attribute__((ext_vector_type(4))) float f32x4;

// ---------------- bf16 split helpers (Ootomo bf16x3 scheme) ----------------

__device__ __forceinline__ short f2bf(float x) {  // RNE float->bf16 bits
    unsigned u = __float_as_uint(x);
    unsigned r = (u + 0x7FFFu + ((u >> 16) & 1u)) >> 16;
    return (short)r;
}
__device__ __forceinline__ float bf2f(short s) {
    return __uint_as_float(((unsigned)(unsigned short)s) << 16);
}
__device__ __forceinline__ void split1(float v, short& h, short& l) {
    h = f2bf(v);
    l = f2bf(v - bf2f(h));
}

// Load 8 consecutive floats (16B-aligned), split into hi/lo bf16 fragments.
__device__ __forceinline__ void split8(const float* __restrict__ p, bool ok, bf16x8& hi,
                                       bf16x8& lo) {
    float v[8];
    if (ok) {
        float4 x0 = ((const float4*)p)[0];
        float4 x1 = ((const float4*)p)[1];
        v[0] = x0.x; v[1] = x0.y; v[2] = x0.z; v[3] = x0.w;
        v[4] = x1.x; v[5] = x1.y; v[6] = x1.z; v[7] = x1.w;
    } else {
#pragma unroll
        for (int j = 0; j < 8; j++) v[j] = 0.f;
    }
#pragma unroll
    for (int j = 0; j < 8; j++) {
        short hb = f2bf(v[j]);
        hi[j] = hb;
        lo[j] = f2bf(v[j] - bf2f(hb));
    }
}

__device__ __forceinline__ float fast_tanh(float x) {
    x = fminf(fmaxf(x, -15.f), 15.f);
    float t = __expf(2.f * x);
    return __fdividef(t - 1.f, t + 1.f);
}

__device__ __forceinline__ void fma4(float4& acc, float v, const float4& x) {
    acc.x = fmaf(v, x.x, acc.x);
    acc.y = fmaf(v, x.y, acc.y);
    acc.z = fmaf(v, x.z, acc.z);
    acc.w = fmaf(v, x.w, acc.w);
}

__device__ __forceinline__ void red4(float4& a) {
    a.x += __shfl_xor(a.x, 16); a.y += __shfl_xor(a.y, 16);
    a.z += __shfl_xor(a.z, 16); a.w += __shfl_xor(a.w, 16);
    a.x += __shfl_xor(a.x, 32); a.y += __shfl_xor(a.y, 32);
    a.z += __shfl_xor(a.z, 32); a.w += __shfl_xor(a.w, 32);
}

// ---------------- dtype forensics (masks / indices) ----------------
// modes: 0=u8/bool, 1=int32, 2=float32, 3=int64, 4=float64
__global__ __launch_bounds__(256) void forensic_kernel(const unsigned int* __restrict__ mask_w,
                                                       const unsigned int* __restrict__ idx_w,
                                                       int nw_mask, int nw_idx,
                                                       int* __restrict__ flags) {
    __shared__ int sm[6];
    int t = threadIdx.x;
    if (t < 6) sm[t] = 0;
    __syncthreads();
    int m_gt1 = 0, m_f32 = 0, m_f64 = 0, m_oddnz = 0, i_hi = 0, i_oddnz = 0;
    for (int i = t; i < nw_mask; i += 256) {
        unsigned int w = mask_w[i];
        if (w > 1u && w != 0x3F800000u && w != 0x3FF00000u) m_gt1++;
        if (w == 0x3F800000u) m_f32++;
        if ((i & 1) && w == 0x3FF00000u) m_f64++;
        if ((i & 1) && w != 0u) m_oddnz++;
    }
    for (int i = t; i < nw_idx; i += 256) {
        unsigned int v = idx_w[i];
        if (v >= 0x20000000u) i_hi++;
        if ((i & 1) && v != 0u) i_oddnz++;
    }
    atomicAdd(&sm[0], m_gt1);
    atomicAdd(&sm[1], m_f32);
    atomicAdd(&sm[2], m_f64);
    atomicAdd(&sm[3], m_oddnz);
    atomicAdd(&sm[4], i_hi);
    atomicAdd(&sm[5], i_oddnz);
    __syncthreads();
    if (t == 0) {
        int mmode;
        if (sm[1] > 50) mmode = 2;
        else if (sm[2] > 50) mmode = 4;
        else if (sm[0] > 50) mmode = 0;
        else if (sm[3] > 50) mmode = 1;
        else mmode = 3;
        int imode;
        if (sm[4] > (nw_idx * 3) / 4) imode = 2;
        else if (sm[4] > nw_idx / 4) imode = 4;
        else if (sm[5] > 50) imode = 1;
        else imode = 3;
        flags[0] = mmode;
        flags[1] = imode;
    }
}

__device__ __forceinline__ int fetch_idx(const void* p, int e, int mode) {
    switch (mode) {
        case 1: return ((const int*)p)[e];
        case 3: return (int)(((const long long*)p)[e]);
        case 2: return (int)(((const float*)p)[e]);
        default: return (int)(((const double*)p)[e]);
    }
}

__device__ __forceinline__ bool conv_one(const void* m, int mode, int i) {
    switch (mode) {
        case 0: return ((const unsigned char*)m)[i] != 0;
        case 1: return ((const int*)m)[i] != 0;
        case 2: return ((const float*)m)[i] != 0.f;
        case 3: return ((const long long*)m)[i] != 0;
        default: return ((const double*)m)[i] != 0.0;
    }
}

// Both masks in one launch.
__global__ __launch_bounds__(256) void conv_masks(const void* __restrict__ m1,
                                                  const void* __restrict__ m2,
                                                  const int* __restrict__ flags, int n,
                                                  unsigned char* __restrict__ o1,
                                                  unsigned char* __restrict__ o2) {
    int mode = flags[0];
    int i = blockIdx.x * 256 + threadIdx.x;
    if (i >= n) return;
    o1[i] = conv_one(m1, mode, i) ? 1 : 0;
    o2[i] = conv_one(m2, mode, i) ? 1 : 0;
}

// ---------------- CSR build: two-level bucket sort, block-aggregated binning --------

__global__ __launch_bounds__(256) void bucket_hist(const void* __restrict__ row,
                                                   const int* __restrict__ flags, int e_cnt,
                                                   int n, int shift, int nb,
                                                   int* __restrict__ bcnt) {
    __shared__ int hist[2048];
    int t = threadIdx.x;
    for (int i = t; i < nb; i += 256) hist[i] = 0;
    __syncthreads();
    int imode = flags[1];
    for (int e = blockIdx.x * 256 + t; e < e_cnt; e += gridDim.x * 256) {
        int r = fetch_idx(row, e, imode);
        if ((unsigned)r < (unsigned)n) atomicAdd(&hist[r >> shift], 1);
    }
    __syncthreads();
    for (int i = t; i < nb; i += 256)
        if (hist[i]) atomicAdd(&bcnt[i], hist[i]);
}

// bptr: in = counts, out = exclusive offsets; also fills bcur and row_ptr[n].
__global__ __launch_bounds__(1024) void bucket_scan(int* __restrict__ bptr, int nb,
                                                    int* __restrict__ bcur, int n,
                                                    int* __restrict__ row_ptr) {
    __shared__ int sh[1024];
    int t = threadIdx.x;
    int i0 = t * 2, i1 = t * 2 + 1;
    int a = (i0 < nb) ? bptr[i0] : 0;
    int b = (i1 < nb) ? bptr[i1] : 0;
    int s = a + b;
    sh[t] = s;
    __syncthreads();
    for (int off = 1; off < 1024; off <<= 1) {
        int u = (t >= off) ? sh[t - off] : 0;
        __syncthreads();
        sh[t] += u;
        __syncthreads();
    }
    int base = sh[t] - s;  // exclusive prefix
    if (i0 < nb) { bptr[i0] = base; bcur[i0] = base; }
    if (i1 < nb) { bptr[i1] = base + a; bcur[i1] = base + a; }
    if (t == 1023) {
        bptr[nb] = sh[1023];
        row_ptr[n] = sh[1023];
    }
}

// Block-aggregated binning; 2048 edges/block, register-cached.
__global__ __launch_bounds__(256) void bin_pass2(const void* __restrict__ row,
                                                 const void* __restrict__ col,
                                                 const float* __restrict__ vals,
                                                 const int* __restrict__ flags, int e_cnt, int n,
                                                 int shift, int nb, int* __restrict__ bcur,
                                                 int2* __restrict__ rcbin,
                                                 float* __restrict__ valbin) {
    __shared__ int hist[2048];
    __shared__ int base[2048];
    int t = threadIdx.x;
    int e0 = blockIdx.x * 2048;
    if (e0 >= e_cnt) return;
    int imode = flags[1];
    for (int i = t; i < nb; i += 256) hist[i] = 0;
    __syncthreads();
    // phase 1: load this thread's 8 edges into registers + LDS histogram
    int rr[8], cc[8];
    float vv[8];
    bool ok[8];
#pragma unroll
    for (int j = 0; j < 8; j++) {
        int e = e0 + j * 256 + t;
        ok[j] = false;
        if (e < e_cnt) {
            int r = fetch_idx(row, e, imode);
            if ((unsigned)r < (unsigned)n) {
                ok[j] = true;
                rr[j] = r;
                int c = fetch_idx(col, e, imode);
                cc[j] = ((unsigned)c < (unsigned)n) ? c : 0;
                vv[j] = vals[e];
                atomicAdd(&hist[r >> shift], 1);
            }
        }
    }
    __syncthreads();
    // phase 2: reserve one contiguous range per bucket (1 global atomic each)
    for (int i = t; i < nb; i += 256) {
        int c = hist[i];
        base[i] = c ? atomicAdd(&bcur[i], c) : 0;
        hist[i] = 0;  // reuse as within-block cursor
    }
    __syncthreads();
    // phase 3: scatter from registers into reserved ranges
#pragma unroll
    for (int j = 0; j < 8; j++) {
        if (ok[j]) {
            int bk = rr[j] >> shift;
            int pos = base[bk] + atomicAdd(&hist[bk], 1);
            rcbin[pos] = make_int2(rr[j], cc[j]);
            valbin[pos] = vv[j];
        }
    }
}

// One block per bucket, 512 threads. rows-per-bucket <= 1024.
__global__ __launch_bounds__(512) void csr_finalize(const int* __restrict__ bptr,
                                                    const int2* __restrict__ rcbin,
                                                    const float* __restrict__ valbin, int n,
                                                    int shift, int* __restrict__ row_ptr,
                                                    int* __restrict__ col_s,
                                                    float* __restrict__ val_s) {
    __shared__ int cnt[1024];
    __shared__ int curs[1024];
    __shared__ int red[512];
    int b = blockIdx.x, t = threadIdx.x;
    int rpb = 1 << shift;
    int r0 = b << shift;
    int rows = n - r0;
    if (rows <= 0) return;
    if (rows > rpb) rows = rpb;
    int ebase = bptr[b], eend = bptr[b + 1];
    for (int i = t; i < rows; i += 512) cnt[i] = 0;
    __syncthreads();
    for (int e = ebase + t; e < eend; e += 512) atomicAdd(&cnt[rcbin[e].x - r0], 1);
    __syncthreads();
    // exclusive scan of cnt[0..rows): 2 values per thread + block scan
    int v[2], s = 0;
#pragma unroll
    for (int j = 0; j < 2; j++) {
        int idx = t * 2 + j;
        v[j] = (idx < rows) ? cnt[idx] : 0;
        s += v[j];
    }
    red[t] = s;
    __syncthreads();
    for (int off = 1; off < 512; off <<= 1) {
        int u = (t >= off) ? red[t - off] : 0;
        __syncthreads();
        red[t] += u;
        __syncthreads();
    }
    int run = ebase + red[t] - s;
#pragma unroll
    for (int j = 0; j < 2; j++) {
        int idx = t * 2 + j;
        if (idx < rows) {
            row_ptr[r0 + idx] = run;
            curs[idx] = run;
            run += v[j];
        }
    }
    __syncthreads();
    for (int e = ebase + t; e < eend; e += 512) {
        int2 rc = rcbin[e];
        float vv = valbin[e];
        int pos = atomicAdd(&curs[rc.x - r0], 1);
        col_s[pos] = rc.y;
        val_s[pos] = vv;
    }
}

// ---------------- SpMM: ax = A @ x  (CSR, one wave per row) ----------------

__global__ __launch_bounds__(256) void spmm_dual(const float* __restrict__ X,
                                                 const int* __restrict__ row_ptr,
                                                 const int* __restrict__ col_s,
                                                 const float* __restrict__ val_s,
                                                 const unsigned char* __restrict__ mask, int n,
                                                 float* __restrict__ ax_m,
                                                 float* __restrict__ ax_f) {
    int gid = blockIdx.x * 256 + threadIdx.x;
    int r = gid >> 6;
    if (r >= n) return;
    int lane = threadIdx.x & 63;
    int g = lane >> 4, sub = lane & 15;
    int s = row_ptr[r], e = row_ptr[r + 1];
    int cnt = e - s;
    int myc = 0;
    float myvf = 0.f, myvm = 0.f;
    if (lane < cnt) {
        myc = col_s[s + lane];
        float v = val_s[s + lane];
        myvf = v;
        myvm = mask[myc] ? 0.f : v;
    }
    int cmain = cnt > 64 ? 64 : cnt;
    float4 fA = {0, 0, 0, 0}, fB = {0, 0, 0, 0}, mA = {0, 0, 0, 0}, mB = {0, 0, 0, 0};
    for (int i = 0; i < cmain; i += 16) {
        int i0 = i + g, i1 = i + 4 + g, i2 = i + 8 + g, i3 = i + 12 + g;
        int c0 = __shfl(myc, i0), c1 = __shfl(myc, i1);
        int c2 = __shfl(myc, i2), c3 = __shfl(myc, i3);
        float vf0 = __shfl(myvf, i0), vf1 = __shfl(myvf, i1);
        float vf2 = __shfl(myvf, i2), vf3 = __shfl(myvf, i3);
        float vm0 = __shfl(myvm, i0), vm1 = __shfl(myvm, i1);
        float vm2 = __shfl(myvm, i2), vm3 = __shfl(myvm, i3);
        if (i0 < cmain) {
            float4 x = *(const float4*)(X + (size_t)c0 * 64 + sub * 4);
            fma4(fA, vf0, x);
            fma4(mA, vm0, x);
        }
        if (i1 < cmain) {
            float4 x = *(const float4*)(X + (size_t)c1 * 64 + sub * 4);
            fma4(fB, vf1, x);
            fma4(mB, vm1, x);
        }
        if (i2 < cmain) {
            float4 x = *(const float4*)(X + (size_t)c2 * 64 + sub * 4);
            fma4(fA, vf2, x);
            fma4(mA, vm2, x);
        }
        if (i3 < cmain) {
            float4 x = *(const float4*)(X + (size_t)c3 * 64 + sub * 4);
            fma4(fB, vf3, x);
            fma4(mB, vm3, x);
        }
    }
    for (int i = 64 + g; i < cnt; i += 4) {  // rare overflow rows
        int c = col_s[s + i];
        float v = val_s[s + i];
        float vm = mask[c] ? 0.f : v;
        float4 x = *(const float4*)(X + (size_t)c * 64 + sub * 4);
        fma4(fA, v, x);
        fma4(mA, vm, x);
    }
    fA.x += fB.x; fA.y += fB.y; fA.z += fB.z; fA.w += fB.w;
    mA.x += mB.x; mA.y += mB.y; mA.z += mB.z; mA.w += mB.w;
    red4(fA);
    red4(mA);
    if (g == 0) {
        *(float4*)(ax_f + (size_t)r * 64 + sub * 4) = fA;
        *(float4*)(ax_m + (size_t)r * 64 + sub * 4) = mA;
    }
}

// Single-output masked SpMM; masked edges skip the gather entirely.
__global__ __launch_bounds__(256) void spmm_one(const float* __restrict__ X,
                                                const int* __restrict__ row_ptr,
                                                const int* __restrict__ col_s,
                                                const float* __restrict__ val_s,
                                                const unsigned char* __restrict__ mask, int n,
                                                float* __restrict__ ax) {
    int gid = blockIdx.x * 256 + threadIdx.x;
    int r = gid >> 6;
    if (r >= n) return;
    int lane = threadIdx.x & 63;
    int g = lane >> 4, sub = lane & 15;
    int s = row_ptr[r], e = row_ptr[r + 1];
    int cnt = e - s;
    int myc = 0;
    float myv = 0.f;
    if (lane < cnt) {
        myc = col_s[s + lane];
        float v = val_s[s + lane];
        myv = mask[myc] ? 0.f : v;
    }
    int cmain = cnt > 64 ? 64 : cnt;
    float4 aA = {0, 0, 0, 0}, aB = {0, 0, 0, 0};
    for (int i = 0; i < cmain; i += 16) {
        int i0 = i + g, i1 = i + 4 + g, i2 = i + 8 + g, i3 = i + 12 + g;
        int c0 = __shfl(myc, i0), c1 = __shfl(myc, i1);
        int c2 = __shfl(myc, i2), c3 = __shfl(myc, i3);
        float v0 = __shfl(myv, i0), v1 = __shfl(myv, i1);
        float v2 = __shfl(myv, i2), v3 = __shfl(myv, i3);
        if (i0 < cmain && v0 != 0.f) {
            float4 x = *(const float4*)(X + (size_t)c0 * 64 + sub * 4);
            fma4(aA, v0, x);
        }
        if (i1 < cmain && v1 != 0.f) {
            float4 x = *(const float4*)(X + (size_t)c1 * 64 + sub * 4);
            fma4(aB, v1, x);
        }
        if (i2 < cmain && v2 != 0.f) {
            float4 x = *(const float4*)(X + (size_t)c2 * 64 + sub * 4);
            fma4(aA, v2, x);
        }
        if (i3 < cmain && v3 != 0.f) {
            float4 x = *(const float4*)(X + (size_t)c3 * 64 + sub * 4);
            fma4(aB, v3, x);
        }
    }
    for (int i = 64 + g; i < cnt; i += 4) {
        int c = col_s[s + i];
        if (mask[c]) continue;
        float v = val_s[s + i];
        float4 x = *(const float4*)(X + (size_t)c * 64 + sub * 4);
        fma4(aA, v, x);
    }
    aA.x += aB.x; aA.y += aB.y; aA.z += aB.z; aA.w += aB.w;
    red4(aA);
    if (g == 0) *(float4*)(ax + (size_t)r * 64 + sub * 4) = aA;
}

// ---------------- fused kernel A: embed GEMM (bias+PReLU) -> LDS bf16 planes -> fc GEMM ----
// Round-5 fix: gemm_tanh was VALU-bound (45% busy, MfmaUtil 8%) on redundant
// bf16 split math: each of 4 waves re-split8 the full f32 tile (fc stage) and
// the X tile. Now: (1) X tile staged cooperatively into bf16 hi/lo LDS planes
// (split once per element), (2) embed output written to LDS already split.
// Fragment reads are raw ds_read_b128, zero conversion VALU. Bit-identical math.
// Stride 72 bf16 (144B) -> 2-way bank aliasing (free).

template <int PP>
__global__ __launch_bounds__(256) void gemm_tanh(const float* __restrict__ X,
                                                 const float* __restrict__ Wg,
                                                 const float* __restrict__ b,
                                                 const float* __restrict__ a,
                                                 const float* __restrict__ fcw,
                                                 const float* __restrict__ fcb, int n,
                                                 float* __restrict__ s_sums) {
    __shared__ __align__(16) short xhi[16][72], xlo[16][72];
    __shared__ __align__(16) short ehi[PP][16][72], elo[PP][16][72];
    int t = threadIdx.x;
    int wv = t >> 6, lane = t & 63, nl = lane & 15, q = lane >> 4;
    int colg = wv * 16 + nl;
    int srow = t >> 4, scol = (t & 15) * 4;  // staging coords: 16 rows x 16 col-blocks
    bf16x8 whi[PP][2], wlo[PP][2];
    float bias[PP], slope[PP];
#pragma unroll
    for (int p = 0; p < PP; p++) {
#pragma unroll
        for (int kk = 0; kk < 2; kk++)
            split8(Wg + p * 4096 + colg * 64 + kk * 32 + q * 8, true, whi[p][kk], wlo[p][kk]);
        bias[p] = b[p * 64 + colg];
        slope[p] = a[p];
    }
    bf16x8 fhi[2], flo[2];
#pragma unroll
    for (int kk = 0; kk < 2; kk++)
        split8(fcw + colg * 64 + kk * 32 + q * 8, true, fhi[kk], flo[kk]);
    float fbias = fcb[colg];
    float ssum[PP];
#pragma unroll
    for (int p = 0; p < PP; p++) ssum[p] = 0.f;

    int ntiles = (n + 15) >> 4;
    for (int rt = blockIdx.x; rt < ntiles; rt += gridDim.x) {
        // stage X tile -> bf16 planes (split once per element, cooperatively)
        int gr = rt * 16 + srow;
        float4 xv = (gr < n) ? *(const float4*)(X + (size_t)gr * 64 + scol)
                             : make_float4(0.f, 0.f, 0.f, 0.f);
        short4 hh, ll;
        split1(xv.x, hh.x, ll.x);
        split1(xv.y, hh.y, ll.y);
        split1(xv.z, hh.z, ll.z);
        split1(xv.w, hh.w, ll.w);
        *(short4*)(&xhi[srow][scol]) = hh;
        *(short4*)(&xlo[srow][scol]) = ll;
        __syncthreads();
        bf16x8 ah[2], al[2];
#pragma unroll
        for (int kk = 0; kk < 2; kk++) {
            ah[kk] = *(const bf16x8*)(&xhi[nl][kk * 32 + q * 8]);
            al[kk] = *(const bf16x8*)(&xlo[nl][kk * 32 + q * 8]);
        }
#pragma unroll
        for (int p = 0; p < PP; p++) {
            f32x4 acc = {0.f, 0.f, 0.f, 0.f};
            acc = __builtin_amdgcn_mfma_f32_16x16x32_bf16(ah[0], whi[p][0], acc, 0, 0, 0);
            acc = __builtin_amdgcn_mfma_f32_16x16x32_bf16(ah[1], whi[p][1], acc, 0, 0, 0);
            acc = __builtin_amdgcn_mfma_f32_16x16x32_bf16(al[0], whi[p][0], acc, 0, 0, 0);
            acc = __builtin_amdgcn_mfma_f32_16x16x32_bf16(al[1], whi[p][1], acc, 0, 0, 0);
            acc = __builtin_amdgcn_mfma_f32_16x16x32_bf16(ah[0], wlo[p][0], acc, 0, 0, 0);
            acc = __builtin_amdgcn_mfma_f32_16x16x32_bf16(ah[1], wlo[p][1], acc, 0, 0, 0);
            acc = __builtin_amdgcn_mfma_f32_16x16x32_bf16(al[0], wlo[p][0], acc, 0, 0, 0);
            acc = __builtin_amdgcn_mfma_f32_16x16x32_bf16(al[1], wlo[p][1], acc, 0, 0, 0);
#pragma unroll
            for (int i = 0; i < 4; i++) {
                float o = acc[i] + bias[p];
                o = (o > 0.f) ? o : slope[p] * o;
                short hb, lb;
                split1(o, hb, lb);
                ehi[p][q * 4 + i][colg] = hb;
                elo[p][q * 4 + i][colg] = lb;
            }
        }
        __syncthreads();
#pragma unroll
        for (int p = 0; p < PP; p++) {
            bf16x8 eh[2], el[2];
#pragma unroll
            for (int kk = 0; kk < 2; kk++) {
                eh[kk] = *(const bf16x8*)(&ehi[p][nl][kk * 32 + q * 8]);
                el[kk] = *(const bf16x8*)(&elo[p][nl][kk * 32 + q * 8]);
            }
            f32x4 acc = {0.f, 0.f, 0.f, 0.f};
            acc = __builtin_amdgcn_mfma_f32_16x16x32_bf16(eh[0], fhi[0], acc, 0, 0, 0);
            acc = __builtin_amdgcn_mfma_f32_16x16x32_bf16(eh[1], fhi[1], acc, 0, 0, 0);
            acc = __builtin_amdgcn_mfma_f32_16x16x32_bf16(el[0], fhi[0], acc, 0, 0, 0);
            acc = __builtin_amdgcn_mfma_f32_16x16x32_bf16(el[1], fhi[1], acc, 0, 0, 0);
            acc = __builtin_amdgcn_mfma_f32_16x16x32_bf16(eh[0], flo[0], acc, 0, 0, 0);
            acc = __builtin_amdgcn_mfma_f32_16x16x32_bf16(eh[1], flo[1], acc, 0, 0, 0);
#pragma unroll
            for (int i = 0; i < 4; i++) {
                int r = rt * 16 + q * 4 + i;
                if (r < n) ssum[p] += fast_tanh(acc[i] + fbias);
            }
        }
        // next iteration's X-stage writes xhi/xlo: all waves finished reading
        // them before the 2nd barrier of THIS tile, so no extra barrier needed.
    }
#pragma unroll
    for (int p = 0; p < PP; p++) {
        float s = ssum[p];
        s += __shfl_xor(s, 16);
        s += __shfl_xor(s, 32);
        if (q == 0) atomicAdd(&s_sums[p * 64 + colg], s);
    }
}

// ---------------- fused kernel B: recompute embed GEMM, mix with beta, write out -----------

template <int PP>
__global__ __launch_bounds__(256) void gemm_mix(const float* __restrict__ X,
                                                const float* __restrict__ Wg,
                                                const float* __restrict__ b,
                                                const float* __restrict__ a,
                                                const float* __restrict__ beta, int n,
                                                float* __restrict__ out, int accum) {
    int t = threadIdx.x;
    int wv = t >> 6, lane = t & 63, nl = lane & 15, q = lane >> 4;
    int colg = wv * 16 + nl;
    bf16x8 whi[PP][2], wlo[PP][2];
    float bias[PP], slope[PP], bet[PP];
#pragma unroll
    for (int p = 0; p < PP; p++) {
#pragma unroll
        for (int kk = 0; kk < 2; kk++)
            split8(Wg + p * 4096 + colg * 64 + kk * 32 + q * 8, true, whi[p][kk], wlo[p][kk]);
        bias[p] = b[p * 64 + colg];
        slope[p] = a[p];
        bet[p] = beta[p];
    }
    int ntiles = (n + 15) >> 4;
    for (int rt = blockIdx.x; rt < ntiles; rt += gridDim.x) {
        int rowi = rt * 16 + nl;
        bool ok = rowi < n;
        bf16x8 ah[2], al[2];
#pragma unroll
        for (int kk = 0; kk < 2; kk++)
            split8(X + (size_t)rowi * 64 + kk * 32 + q * 8, ok, ah[kk], al[kk]);
        float mix[4] = {0.f, 0.f, 0.f, 0.f};
#pragma unroll
        for (int p = 0; p < PP; p++) {
            f32x4 acc = {0.f, 0.f, 0.f, 0.f};
            acc = __builtin_amdgcn_mfma_f32_16x16x32_bf16(ah[0], whi[p][0], acc, 0, 0, 0);
            acc = __builtin_amdgcn_mfma_f32_16x16x32_bf16(ah[1], whi[p][1], acc, 0, 0, 0);
            acc = __builtin_amdgcn_mfma_f32_16x16x32_bf16(al[0], whi[p][0], acc, 0, 0, 0);
            acc = __builtin_amdgcn_mfma_f32_16x16x32_bf16(al[1], whi[p][1], acc, 0, 0, 0);
            acc = __builtin_amdgcn_mfma_f32_16x16x32_bf16(ah[0], wlo[p][0], acc, 0, 0, 0);
            acc = __builtin_amdgcn_mfma_f32_16x16x32_bf16(ah[1], wlo[p][1], acc, 0, 0, 0);
            acc = __builtin_amdgcn_mfma_f32_16x16x32_bf16(al[0], wlo[p][0], acc, 0, 0, 0);
            acc = __builtin_amdgcn_mfma_f32_16x16x32_bf16(al[1], wlo[p][1], acc, 0, 0, 0);
#pragma unroll
            for (int i = 0; i < 4; i++) {
                float o = acc[i] + bias[p];
                o = (o > 0.f) ? o : slope[p] * o;
                mix[i] = fmaf(bet[p], o, mix[i]);
            }
        }
#pragma unroll
        for (int i = 0; i < 4; i++) {
            int r = rt * 16 + q * 4 + i;
            if (r < n) {
                size_t idx = (size_t)r * 64 + colg;
                out[idx] = accum ? (out[idx] + mix[i]) : mix[i];
            }
        }
    }
}

__global__ __launch_bounds__(64) void compute_beta(const float* __restrict__ s_sums,
                                                   const float* __restrict__ att, int n, int P,
                                                   float* __restrict__ beta) {
    int lane = threadIdx.x;
    float av = att[lane];
    float l[8];
    for (int p = 0; p < P; p++) l[p] = s_sums[p * 64 + lane] * av;
#pragma unroll
    for (int off = 32; off > 0; off >>= 1)
        for (int p = 0; p < 8; p++)
            if (p < P) l[p] += __shfl_down(l[p], off);
    if (lane == 0) {
        const float inv = 1.0f / (float)n;
        float m = -1e30f;
        for (int p = 0; p < P; p++) {
            l[p] *= inv;
            m = fmaxf(m, l[p]);
        }
        float s = 0.f;
        for (int p = 0; p < P; p++) {
            l[p] = __expf(l[p] - m);
            s += l[p];
        }
        for (int p = 0; p < P; p++) beta[p] = l[p] / s;
    }
}

// ---------------- driver ----------------

extern "C" void kernel_launch(void* const* d_in, const int* in_sizes, int n_in,
                              void* d_out, int out_size, void* d_ws, size_t ws_size,
                              hipStream_t stream) {
    const float* h = (const float*)d_in[0];
    const float* W = (const float*)d_in[1];
    const float* b = (const float*)d_in[2];
    const float* a = (const float*)d_in[3];
    const float* fc_w = (const float*)d_in[4];
    const float* fc_b = (const float*)d_in[5];
    const float* att = (const float*)d_in[6];
    const float* adj = (const float*)d_in[7];
    const void* row = d_in[8];
    const void* col = d_in[9];
    const void* mask1 = d_in[10];
    const void* mask2 = d_in[11];
    float* out = (float*)d_out;

    int P = in_sizes[3];
    if (P < 1 || P > 8) P = 3;
    int N = in_sizes[0] / 64;
    int E = in_sizes[7];

    // bucket geometry: rows/bucket = 1<<shift, buckets <= 2048
    int shift = 8;
    while (((N >> shift) + 1) > 2048) shift++;
    int NB = (N >> shift) + 1;

    char* w = (char*)d_ws;
    auto alloc = [&](size_t bytes) {
        void* p = (void*)w;
        w += (bytes + 255) & ~(size_t)255;
        return p;
    };
    int* row_ptr = (int*)alloc((size_t)(N + 1) * 4);
    int* col_s = (int*)alloc((size_t)E * 4);
    float* val_s = (float*)alloc((size_t)E * 4);
    int* bptr = (int*)alloc((size_t)(NB + 1) * 4);
    int* bcur = (int*)alloc((size_t)NB * 4);
    int2* rcbin = (int2*)alloc((size_t)E * 8);
    float* valbin = (float*)alloc((size_t)E * 4);
    unsigned char* m1c = (unsigned char*)alloc(N);
    unsigned char* m2c = (unsigned char*)alloc(N);
    float* axm = (float*)alloc((size_t)N * 64 * 4);  // A @ (x * ~mask)
    float* axf = (float*)alloc((size_t)N * 64 * 4);  // A @ x
    float* s_sums = (float*)alloc(8 * 64 * 4);
    float* beta = (float*)alloc(8 * 4);
    int* flags = (int*)alloc(256);

    int nw_mask = N / 4 > 25000 ? 25000 : N / 4;
    int nw_idx = E / 4 > 25000 ? 25000 : E / 4;
    forensic_kernel<<<1, 256, 0, stream>>>((const unsigned int*)mask1, (const unsigned int*)row,
                                           nw_mask, nw_idx, flags);
    conv_masks<<<(N + 255) / 256, 256, 0, stream>>>(mask1, mask2, flags, N, m1c, m2c);

    hipMemsetAsync(bptr, 0, (size_t)(NB + 1) * 4, stream);
    bucket_hist<<<1024, 256, 0, stream>>>(row, flags, E, N, shift, NB, bptr);
    bucket_scan<<<1, 1024, 0, stream>>>(bptr, NB, bcur, N, row_ptr);
    int bin_blocks = (E + 2047) / 2048;
    bin_pass2<<<bin_blocks, 256, 0, stream>>>(row, col, adj, flags, E, N, shift, NB, bcur, rcbin,
                                              valbin);
    csr_finalize<<<NB, 512, 0, stream>>>(bptr, rcbin, valbin, N, shift, row_ptr, col_s, val_s);

    int spmm_grid = ((size_t)N * 64 + 255) / 256;  // one wave per row
    int tanh_blocks = 2048;
    int mix_blocks = 1536;

    // tail: ax -> [A: embed GEMM + fc + tanh-sum] -> beta -> [B: recompute + mix]
    auto tail = [&](const float* ax, float* dst) {
        hipMemsetAsync(s_sums, 0, 8 * 64 * 4, stream);
        if (P == 3) {
            gemm_tanh<3><<<tanh_blocks, 256, 0, stream>>>(ax, W, b, a, fc_w, fc_b, N, s_sums);
        } else {
            for (int p = 0; p < P; p++)
                gemm_tanh<1><<<tanh_blocks, 256, 0, stream>>>(ax, W + p * 4096, b + p * 64, a + p,
                                                              fc_w, fc_b, N, s_sums + p * 64);
        }
        compute_beta<<<1, 64, 0, stream>>>(s_sums, att, N, P, beta);
        if (P == 3) {
            gemm_mix<3><<<mix_blocks, 256, 0, stream>>>(ax, W, b, a, beta, N, dst, 0);
        } else {
            for (int p = 0; p < P; p++)
                gemm_mix<1><<<mix_blocks, 256, 0, stream>>>(ax, W + p * 4096, b + p * 64, a + p,
                                                            beta + p, N, dst, p != 0);
        }
    };

    // pass 0 + 1 share one edge sweep: ax_masked and ax_full from a single gather
    spmm_dual<<<spmm_grid, 256, 0, stream>>>(h, row_ptr, col_s, val_s, m1c, N, axm, axf);
    tail(axm, out);                       // z_mp
    tail(axf, out + (size_t)N * 64);      // z_mp2
    // pass 2 decodes from z_mp (in d_out), masked by mask2 (gather skipped when masked)
    spmm_one<<<spmm_grid, 256, 0, stream>>>(out, row_ptr, col_s, val_s, m2c, N, axm);
    tail(axm, out + (size_t)2 * N * 64);  // x_recon
}

// Round 7
// 591.220 us; speedup vs baseline: 1.1245x; 1.1245x over previous
//
#include <hip/hip_runtime.h>
#include <hip/hip_bf16.h>

typedef __hip_bfloat16 bf16;
typedef __attribute__((ext_vector_type(8))) short bf16x8;  // 8 bf16 in 4 VGPRs
typedef __attribute__((ext_vector_type(4))) float f32x4;

// ---------------- bf16 split helpers (Ootomo bf16x3 scheme) ----------------

__device__ __forceinline__ short f2bf(float x) {  // RNE float->bf16 bits
    unsigned u = __float_as_uint(x);
    unsigned r = (u + 0x7FFFu + ((u >> 16) & 1u)) >> 16;
    return (short)r;
}
__device__ __forceinline__ float bf2f(short s) {
    return __uint_as_float(((unsigned)(unsigned short)s) << 16);
}
__device__ __forceinline__ void split1(float v, short& h, short& l) {
    h = f2bf(v);
    l = f2bf(v - bf2f(h));
}

// Load 8 consecutive floats (16B-aligned), split into hi/lo bf16 fragments.
__device__ __forceinline__ void split8(const float* __restrict__ p, bool ok, bf16x8& hi,
                                       bf16x8& lo) {
    float v[8];
    if (ok) {
        float4 x0 = ((const float4*)p)[0];
        float4 x1 = ((const float4*)p)[1];
        v[0] = x0.x; v[1] = x0.y; v[2] = x0.z; v[3] = x0.w;
        v[4] = x1.x; v[5] = x1.y; v[6] = x1.z; v[7] = x1.w;
    } else {
#pragma unroll
        for (int j = 0; j < 8; j++) v[j] = 0.f;
    }
#pragma unroll
    for (int j = 0; j < 8; j++) {
        short hb = f2bf(v[j]);
        hi[j] = hb;
        lo[j] = f2bf(v[j] - bf2f(hb));
    }
}

__device__ __forceinline__ float fast_tanh(float x) {
    x = fminf(fmaxf(x, -15.f), 15.f);
    float t = __expf(2.f * x);
    return __fdividef(t - 1.f, t + 1.f);
}

__device__ __forceinline__ void fma4(float4& acc, float v, const float4& x) {
    acc.x = fmaf(v, x.x, acc.x);
    acc.y = fmaf(v, x.y, acc.y);
    acc.z = fmaf(v, x.z, acc.z);
    acc.w = fmaf(v, x.w, acc.w);
}

__device__ __forceinline__ void red4(float4& a) {
    a.x += __shfl_xor(a.x, 16); a.y += __shfl_xor(a.y, 16);
    a.z += __shfl_xor(a.z, 16); a.w += __shfl_xor(a.w, 16);
    a.x += __shfl_xor(a.x, 32); a.y += __shfl_xor(a.y, 32);
    a.z += __shfl_xor(a.z, 32); a.w += __shfl_xor(a.w, 32);
}

// ---------------- dtype forensics (masks / indices) ----------------
// modes: 0=u8/bool, 1=int32, 2=float32, 3=int64, 4=float64
__global__ __launch_bounds__(256) void forensic_kernel(const unsigned int* __restrict__ mask_w,
                                                       const unsigned int* __restrict__ idx_w,
                                                       int nw_mask, int nw_idx,
                                                       int* __restrict__ flags) {
    __shared__ int sm[6];
    int t = threadIdx.x;
    if (t < 6) sm[t] = 0;
    __syncthreads();
    int m_gt1 = 0, m_f32 = 0, m_f64 = 0, m_oddnz = 0, i_hi = 0, i_oddnz = 0;
    for (int i = t; i < nw_mask; i += 256) {
        unsigned int w = mask_w[i];
        if (w > 1u && w != 0x3F800000u && w != 0x3FF00000u) m_gt1++;
        if (w == 0x3F800000u) m_f32++;
        if ((i & 1) && w == 0x3FF00000u) m_f64++;
        if ((i & 1) && w != 0u) m_oddnz++;
    }
    for (int i = t; i < nw_idx; i += 256) {
        unsigned int v = idx_w[i];
        if (v >= 0x20000000u) i_hi++;
        if ((i & 1) && v != 0u) i_oddnz++;
    }
    atomicAdd(&sm[0], m_gt1);
    atomicAdd(&sm[1], m_f32);
    atomicAdd(&sm[2], m_f64);
    atomicAdd(&sm[3], m_oddnz);
    atomicAdd(&sm[4], i_hi);
    atomicAdd(&sm[5], i_oddnz);
    __syncthreads();
    if (t == 0) {
        int mmode;
        if (sm[1] > 50) mmode = 2;
        else if (sm[2] > 50) mmode = 4;
        else if (sm[0] > 50) mmode = 0;
        else if (sm[3] > 50) mmode = 1;
        else mmode = 3;
        int imode;
        if (sm[4] > (nw_idx * 3) / 4) imode = 2;
        else if (sm[4] > nw_idx / 4) imode = 4;
        else if (sm[5] > 50) imode = 1;
        else imode = 3;
        flags[0] = mmode;
        flags[1] = imode;
    }
}

__device__ __forceinline__ int fetch_idx(const void* p, int e, int mode) {
    switch (mode) {
        case 1: return ((const int*)p)[e];
        case 3: return (int)(((const long long*)p)[e]);
        case 2: return (int)(((const float*)p)[e]);
        default: return (int)(((const double*)p)[e]);
    }
}

__device__ __forceinline__ bool conv_one(const void* m, int mode, int i) {
    switch (mode) {
        case 0: return ((const unsigned char*)m)[i] != 0;
        case 1: return ((const int*)m)[i] != 0;
        case 2: return ((const float*)m)[i] != 0.f;
        case 3: return ((const long long*)m)[i] != 0;
        default: return ((const double*)m)[i] != 0.0;
    }
}

// Both masks in one launch.
__global__ __launch_bounds__(256) void conv_masks(const void* __restrict__ m1,
                                                  const void* __restrict__ m2,
                                                  const int* __restrict__ flags, int n,
                                                  unsigned char* __restrict__ o1,
                                                  unsigned char* __restrict__ o2) {
    int mode = flags[0];
    int i = blockIdx.x * 256 + threadIdx.x;
    if (i >= n) return;
    o1[i] = conv_one(m1, mode, i) ? 1 : 0;
    o2[i] = conv_one(m2, mode, i) ? 1 : 0;
}

// ---------------- CSR build: two-level bucket sort, block-aggregated binning --------

__global__ __launch_bounds__(256) void bucket_hist(const void* __restrict__ row,
                                                   const int* __restrict__ flags, int e_cnt,
                                                   int n, int shift, int nb,
                                                   int* __restrict__ bcnt) {
    __shared__ int hist[2048];
    int t = threadIdx.x;
    for (int i = t; i < nb; i += 256) hist[i] = 0;
    __syncthreads();
    int imode = flags[1];
    for (int e = blockIdx.x * 256 + t; e < e_cnt; e += gridDim.x * 256) {
        int r = fetch_idx(row, e, imode);
        if ((unsigned)r < (unsigned)n) atomicAdd(&hist[r >> shift], 1);
    }
    __syncthreads();
    for (int i = t; i < nb; i += 256)
        if (hist[i]) atomicAdd(&bcnt[i], hist[i]);
}

// bptr: in = counts, out = exclusive offsets; also fills bcur and row_ptr[n].
__global__ __launch_bounds__(1024) void bucket_scan(int* __restrict__ bptr, int nb,
                                                    int* __restrict__ bcur, int n,
                                                    int* __restrict__ row_ptr) {
    __shared__ int sh[1024];
    int t = threadIdx.x;
    int i0 = t * 2, i1 = t * 2 + 1;
    int a = (i0 < nb) ? bptr[i0] : 0;
    int b = (i1 < nb) ? bptr[i1] : 0;
    int s = a + b;
    sh[t] = s;
    __syncthreads();
    for (int off = 1; off < 1024; off <<= 1) {
        int u = (t >= off) ? sh[t - off] : 0;
        __syncthreads();
        sh[t] += u;
        __syncthreads();
    }
    int base = sh[t] - s;  // exclusive prefix
    if (i0 < nb) { bptr[i0] = base; bcur[i0] = base; }
    if (i1 < nb) { bptr[i1] = base + a; bcur[i1] = base + a; }
    if (t == 1023) {
        bptr[nb] = sh[1023];
        row_ptr[n] = sh[1023];
    }
}

// Block-aggregated binning; 2048 edges/block, register-cached.
__global__ __launch_bounds__(256) void bin_pass2(const void* __restrict__ row,
                                                 const void* __restrict__ col,
                                                 const float* __restrict__ vals,
                                                 const int* __restrict__ flags, int e_cnt, int n,
                                                 int shift, int nb, int* __restrict__ bcur,
                                                 int2* __restrict__ rcbin,
                                                 float* __restrict__ valbin) {
    __shared__ int hist[2048];
    __shared__ int base[2048];
    int t = threadIdx.x;
    int e0 = blockIdx.x * 2048;
    if (e0 >= e_cnt) return;
    int imode = flags[1];
    for (int i = t; i < nb; i += 256) hist[i] = 0;
    __syncthreads();
    // phase 1: load this thread's 8 edges into registers + LDS histogram
    int rr[8], cc[8];
    float vv[8];
    bool ok[8];
#pragma unroll
    for (int j = 0; j < 8; j++) {
        int e = e0 + j * 256 + t;
        ok[j] = false;
        if (e < e_cnt) {
            int r = fetch_idx(row, e, imode);
            if ((unsigned)r < (unsigned)n) {
                ok[j] = true;
                rr[j] = r;
                int c = fetch_idx(col, e, imode);
                cc[j] = ((unsigned)c < (unsigned)n) ? c : 0;
                vv[j] = vals[e];
                atomicAdd(&hist[r >> shift], 1);
            }
        }
    }
    __syncthreads();
    // phase 2: reserve one contiguous range per bucket (1 global atomic each)
    for (int i = t; i < nb; i += 256) {
        int c = hist[i];
        base[i] = c ? atomicAdd(&bcur[i], c) : 0;
        hist[i] = 0;  // reuse as within-block cursor
    }
    __syncthreads();
    // phase 3: scatter from registers into reserved ranges
#pragma unroll
    for (int j = 0; j < 8; j++) {
        if (ok[j]) {
            int bk = rr[j] >> shift;
            int pos = base[bk] + atomicAdd(&hist[bk], 1);
            rcbin[pos] = make_int2(rr[j], cc[j]);
            valbin[pos] = vv[j];
        }
    }
}

// One block per bucket, 512 threads. rows-per-bucket <= 1024.
__global__ __launch_bounds__(512) void csr_finalize(const int* __restrict__ bptr,
                                                    const int2* __restrict__ rcbin,
                                                    const float* __restrict__ valbin, int n,
                                                    int shift, int* __restrict__ row_ptr,
                                                    int* __restrict__ col_s,
                                                    float* __restrict__ val_s) {
    __shared__ int cnt[1024];
    __shared__ int curs[1024];
    __shared__ int red[512];
    int b = blockIdx.x, t = threadIdx.x;
    int rpb = 1 << shift;
    int r0 = b << shift;
    int rows = n - r0;
    if (rows <= 0) return;
    if (rows > rpb) rows = rpb;
    int ebase = bptr[b], eend = bptr[b + 1];
    for (int i = t; i < rows; i += 512) cnt[i] = 0;
    __syncthreads();
    for (int e = ebase + t; e < eend; e += 512) atomicAdd(&cnt[rcbin[e].x - r0], 1);
    __syncthreads();
    // exclusive scan of cnt[0..rows): 2 values per thread + block scan
    int v[2], s = 0;
#pragma unroll
    for (int j = 0; j < 2; j++) {
        int idx = t * 2 + j;
        v[j] = (idx < rows) ? cnt[idx] : 0;
        s += v[j];
    }
    red[t] = s;
    __syncthreads();
    for (int off = 1; off < 512; off <<= 1) {
        int u = (t >= off) ? red[t - off] : 0;
        __syncthreads();
        red[t] += u;
        __syncthreads();
    }
    int run = ebase + red[t] - s;
#pragma unroll
    for (int j = 0; j < 2; j++) {
        int idx = t * 2 + j;
        if (idx < rows) {
            row_ptr[r0 + idx] = run;
            curs[idx] = run;
            run += v[j];
        }
    }
    __syncthreads();
    for (int e = ebase + t; e < eend; e += 512) {
        int2 rc = rcbin[e];
        float vv = valbin[e];
        int pos = atomicAdd(&curs[rc.x - r0], 1);
        col_s[pos] = rc.y;
        val_s[pos] = vv;
    }
}

// ---------------- SpMM: ax = A @ x  (CSR, one wave per row) ----------------
// Round-7: outputs are PRE-SPLIT bf16 hi/lo planes (row-major [N16][64] shorts).
// Downstream GEMMs read MFMA A-fragments directly from these planes -> zero
// conversion VALU and no LDS staging in the tail kernels. Same bytes as f32.

__global__ __launch_bounds__(256) void spmm_dual(const float* __restrict__ X,
                                                 const int* __restrict__ row_ptr,
                                                 const int* __restrict__ col_s,
                                                 const float* __restrict__ val_s,
                                                 const unsigned char* __restrict__ mask, int n,
                                                 short* __restrict__ axm_hi,
                                                 short* __restrict__ axm_lo,
                                                 short* __restrict__ axf_hi,
                                                 short* __restrict__ axf_lo) {
    int gid = blockIdx.x * 256 + threadIdx.x;
    int r = gid >> 6;
    if (r >= n) return;
    int lane = threadIdx.x & 63;
    int g = lane >> 4, sub = lane & 15;
    int s = row_ptr[r], e = row_ptr[r + 1];
    int cnt = e - s;
    int myc = 0;
    float myvf = 0.f, myvm = 0.f;
    if (lane < cnt) {
        myc = col_s[s + lane];
        float v = val_s[s + lane];
        myvf = v;
        myvm = mask[myc] ? 0.f : v;
    }
    int cmain = cnt > 64 ? 64 : cnt;
    float4 fA = {0, 0, 0, 0}, fB = {0, 0, 0, 0}, mA = {0, 0, 0, 0}, mB = {0, 0, 0, 0};
    for (int i = 0; i < cmain; i += 16) {
        int i0 = i + g, i1 = i + 4 + g, i2 = i + 8 + g, i3 = i + 12 + g;
        int c0 = __shfl(myc, i0), c1 = __shfl(myc, i1);
        int c2 = __shfl(myc, i2), c3 = __shfl(myc, i3);
        float vf0 = __shfl(myvf, i0), vf1 = __shfl(myvf, i1);
        float vf2 = __shfl(myvf, i2), vf3 = __shfl(myvf, i3);
        float vm0 = __shfl(myvm, i0), vm1 = __shfl(myvm, i1);
        float vm2 = __shfl(myvm, i2), vm3 = __shfl(myvm, i3);
        if (i0 < cmain) {
            float4 x = *(const float4*)(X + (size_t)c0 * 64 + sub * 4);
            fma4(fA, vf0, x);
            fma4(mA, vm0, x);
        }
        if (i1 < cmain) {
            float4 x = *(const float4*)(X + (size_t)c1 * 64 + sub * 4);
            fma4(fB, vf1, x);
            fma4(mB, vm1, x);
        }
        if (i2 < cmain) {
            float4 x = *(const float4*)(X + (size_t)c2 * 64 + sub * 4);
            fma4(fA, vf2, x);
            fma4(mA, vm2, x);
        }
        if (i3 < cmain) {
            float4 x = *(const float4*)(X + (size_t)c3 * 64 + sub * 4);
            fma4(fB, vf3, x);
            fma4(mB, vm3, x);
        }
    }
    for (int i = 64 + g; i < cnt; i += 4) {  // rare overflow rows
        int c = col_s[s + i];
        float v = val_s[s + i];
        float vm = mask[c] ? 0.f : v;
        float4 x = *(const float4*)(X + (size_t)c * 64 + sub * 4);
        fma4(fA, v, x);
        fma4(mA, vm, x);
    }
    fA.x += fB.x; fA.y += fB.y; fA.z += fB.z; fA.w += fB.w;
    mA.x += mB.x; mA.y += mB.y; mA.z += mB.z; mA.w += mB.w;
    red4(fA);
    red4(mA);
    if (g == 0) {
        size_t o = (size_t)r * 64 + sub * 4;
        short4 h4, l4;
        split1(fA.x, h4.x, l4.x); split1(fA.y, h4.y, l4.y);
        split1(fA.z, h4.z, l4.z); split1(fA.w, h4.w, l4.w);
        *(short4*)(axf_hi + o) = h4;
        *(short4*)(axf_lo + o) = l4;
        split1(mA.x, h4.x, l4.x); split1(mA.y, h4.y, l4.y);
        split1(mA.z, h4.z, l4.z); split1(mA.w, h4.w, l4.w);
        *(short4*)(axm_hi + o) = h4;
        *(short4*)(axm_lo + o) = l4;
    }
}

// Single-output masked SpMM; masked edges skip the gather entirely.
__global__ __launch_bounds__(256) void spmm_one(const float* __restrict__ X,
                                                const int* __restrict__ row_ptr,
                                                const int* __restrict__ col_s,
                                                const float* __restrict__ val_s,
                                                const unsigned char* __restrict__ mask, int n,
                                                short* __restrict__ ax_hi,
                                                short* __restrict__ ax_lo) {
    int gid = blockIdx.x * 256 + threadIdx.x;
    int r = gid >> 6;
    if (r >= n) return;
    int lane = threadIdx.x & 63;
    int g = lane >> 4, sub = lane & 15;
    int s = row_ptr[r], e = row_ptr[r + 1];
    int cnt = e - s;
    int myc = 0;
    float myv = 0.f;
    if (lane < cnt) {
        myc = col_s[s + lane];
        float v = val_s[s + lane];
        myv = mask[myc] ? 0.f : v;
    }
    int cmain = cnt > 64 ? 64 : cnt;
    float4 aA = {0, 0, 0, 0}, aB = {0, 0, 0, 0};
    for (int i = 0; i < cmain; i += 16) {
        int i0 = i + g, i1 = i + 4 + g, i2 = i + 8 + g, i3 = i + 12 + g;
        int c0 = __shfl(myc, i0), c1 = __shfl(myc, i1);
        int c2 = __shfl(myc, i2), c3 = __shfl(myc, i3);
        float v0 = __shfl(myv, i0), v1 = __shfl(myv, i1);
        float v2 = __shfl(myv, i2), v3 = __shfl(myv, i3);
        if (i0 < cmain && v0 != 0.f) {
            float4 x = *(const float4*)(X + (size_t)c0 * 64 + sub * 4);
            fma4(aA, v0, x);
        }
        if (i1 < cmain && v1 != 0.f) {
            float4 x = *(const float4*)(X + (size_t)c1 * 64 + sub * 4);
            fma4(aB, v1, x);
        }
        if (i2 < cmain && v2 != 0.f) {
            float4 x = *(const float4*)(X + (size_t)c2 * 64 + sub * 4);
            fma4(aA, v2, x);
        }
        if (i3 < cmain && v3 != 0.f) {
            float4 x = *(const float4*)(X + (size_t)c3 * 64 + sub * 4);
            fma4(aB, v3, x);
        }
    }
    for (int i = 64 + g; i < cnt; i += 4) {
        int c = col_s[s + i];
        if (mask[c]) continue;
        float v = val_s[s + i];
        float4 x = *(const float4*)(X + (size_t)c * 64 + sub * 4);
        fma4(aA, v, x);
    }
    aA.x += aB.x; aA.y += aB.y; aA.z += aB.z; aA.w += aB.w;
    red4(aA);
    if (g == 0) {
        size_t o = (size_t)r * 64 + sub * 4;
        short4 h4, l4;
        split1(aA.x, h4.x, l4.x); split1(aA.y, h4.y, l4.y);
        split1(aA.z, h4.z, l4.z); split1(aA.w, h4.w, l4.w);
        *(short4*)(ax_hi + o) = h4;
        *(short4*)(ax_lo + o) = l4;
    }
}

// ---------------- fused kernel A: embed GEMM -> LDS bf16 planes -> fc GEMM -> tanh-sum ----
// Round-7: A-fragments read directly from pre-split global planes (16B loads,
// zero conversion VALU), with next-tile prefetch hidden under the fc phase.
// Pad rows (n..ntiles*16) are zeroed -> no bounds predicate on loads.

template <int PP>
__global__ __launch_bounds__(256) void gemm_tanh(const short* __restrict__ Xhi,
                                                 const short* __restrict__ Xlo,
                                                 const float* __restrict__ Wg,
                                                 const float* __restrict__ b,
                                                 const float* __restrict__ a,
                                                 const float* __restrict__ fcw,
                                                 const float* __restrict__ fcb, int n, int ntiles,
                                                 float* __restrict__ s_sums) {
    __shared__ __align__(16) short ehi[PP][16][72], elo[PP][16][72];
    int t = threadIdx.x;
    int wv = t >> 6, lane = t & 63, nl = lane & 15, q = lane >> 4;
    int colg = wv * 16 + nl;
    bf16x8 whi[PP][2], wlo[PP][2];
    float bias[PP], slope[PP];
#pragma unroll
    for (int p = 0; p < PP; p++) {
#pragma unroll
        for (int kk = 0; kk < 2; kk++)
            split8(Wg + p * 4096 + colg * 64 + kk * 32 + q * 8, true, whi[p][kk], wlo[p][kk]);
        bias[p] = b[p * 64 + colg];
        slope[p] = a[p];
    }
    bf16x8 fhi[2], flo[2];
#pragma unroll
    for (int kk = 0; kk < 2; kk++)
        split8(fcw + colg * 64 + kk * 32 + q * 8, true, fhi[kk], flo[kk]);
    float fbias = fcb[colg];
    float ssum[PP];
#pragma unroll
    for (int p = 0; p < PP; p++) ssum[p] = 0.f;

    int rt = blockIdx.x;
    bf16x8 ah[2], al[2];
    if (rt < ntiles) {
        size_t rb = (size_t)(rt * 16 + nl) * 64 + q * 8;
#pragma unroll
        for (int kk = 0; kk < 2; kk++) {
            ah[kk] = *(const bf16x8*)(Xhi + rb + kk * 32);
            al[kk] = *(const bf16x8*)(Xlo + rb + kk * 32);
        }
    }
    for (; rt < ntiles; rt += gridDim.x) {
#pragma unroll
        for (int p = 0; p < PP; p++) {
            f32x4 acc = {0.f, 0.f, 0.f, 0.f};
            acc = __builtin_amdgcn_mfma_f32_16x16x32_bf16(ah[0], whi[p][0], acc, 0, 0, 0);
            acc = __builtin_amdgcn_mfma_f32_16x16x32_bf16(ah[1], whi[p][1], acc, 0, 0, 0);
            acc = __builtin_amdgcn_mfma_f32_16x16x32_bf16(al[0], whi[p][0], acc, 0, 0, 0);
            acc = __builtin_amdgcn_mfma_f32_16x16x32_bf16(al[1], whi[p][1], acc, 0, 0, 0);
            acc = __builtin_amdgcn_mfma_f32_16x16x32_bf16(ah[0], wlo[p][0], acc, 0, 0, 0);
            acc = __builtin_amdgcn_mfma_f32_16x16x32_bf16(ah[1], wlo[p][1], acc, 0, 0, 0);
            acc = __builtin_amdgcn_mfma_f32_16x16x32_bf16(al[0], wlo[p][0], acc, 0, 0, 0);
            acc = __builtin_amdgcn_mfma_f32_16x16x32_bf16(al[1], wlo[p][1], acc, 0, 0, 0);
#pragma unroll
            for (int i = 0; i < 4; i++) {
                float o = acc[i] + bias[p];
                o = (o > 0.f) ? o : slope[p] * o;
                short hb, lb;
                split1(o, hb, lb);
                ehi[p][q * 4 + i][colg] = hb;
                elo[p][q * 4 + i][colg] = lb;
            }
        }
        // prefetch next tile's A-fragments (overlaps the fc phase below)
        int rn = rt + gridDim.x;
        bf16x8 pfh[2], pfl[2];
        if (rn < ntiles) {
            size_t rb = (size_t)(rn * 16 + nl) * 64 + q * 8;
#pragma unroll
            for (int kk = 0; kk < 2; kk++) {
                pfh[kk] = *(const bf16x8*)(Xhi + rb + kk * 32);
                pfl[kk] = *(const bf16x8*)(Xlo + rb + kk * 32);
            }
        }
        __syncthreads();
#pragma unroll
        for (int p = 0; p < PP; p++) {
            bf16x8 eh[2], el[2];
#pragma unroll
            for (int kk = 0; kk < 2; kk++) {
                eh[kk] = *(const bf16x8*)(&ehi[p][nl][kk * 32 + q * 8]);
                el[kk] = *(const bf16x8*)(&elo[p][nl][kk * 32 + q * 8]);
            }
            f32x4 acc = {0.f, 0.f, 0.f, 0.f};
            acc = __builtin_amdgcn_mfma_f32_16x16x32_bf16(eh[0], fhi[0], acc, 0, 0, 0);
            acc = __builtin_amdgcn_mfma_f32_16x16x32_bf16(eh[1], fhi[1], acc, 0, 0, 0);
            acc = __builtin_amdgcn_mfma_f32_16x16x32_bf16(el[0], fhi[0], acc, 0, 0, 0);
            acc = __builtin_amdgcn_mfma_f32_16x16x32_bf16(el[1], fhi[1], acc, 0, 0, 0);
            acc = __builtin_amdgcn_mfma_f32_16x16x32_bf16(eh[0], flo[0], acc, 0, 0, 0);
            acc = __builtin_amdgcn_mfma_f32_16x16x32_bf16(eh[1], flo[1], acc, 0, 0, 0);
#pragma unroll
            for (int i = 0; i < 4; i++) {
                int r = rt * 16 + q * 4 + i;
                if (r < n) ssum[p] += fast_tanh(acc[i] + fbias);
            }
        }
        __syncthreads();  // LDS reads done before next tile's writes
#pragma unroll
        for (int kk = 0; kk < 2; kk++) {
            ah[kk] = pfh[kk];
            al[kk] = pfl[kk];
        }
    }
#pragma unroll
    for (int p = 0; p < PP; p++) {
        float s = ssum[p];
        s += __shfl_xor(s, 16);
        s += __shfl_xor(s, 32);
        if (q == 0) atomicAdd(&s_sums[p * 64 + colg], s);
    }
}

// ---------------- fused kernel B: recompute embed GEMM, mix with beta, write out -----------
// Round-7: no LDS, no split VALU; A-fragments direct from planes + prefetch.

template <int PP>
__global__ __launch_bounds__(256) void gemm_mix(const short* __restrict__ Xhi,
                                                const short* __restrict__ Xlo,
                                                const float* __restrict__ Wg,
                                                const float* __restrict__ b,
                                                const float* __restrict__ a,
                                                const float* __restrict__ beta, int n, int ntiles,
                                                float* __restrict__ out, int accum) {
    int t = threadIdx.x;
    int wv = t >> 6, lane = t & 63, nl = lane & 15, q = lane >> 4;
    int colg = wv * 16 + nl;
    bf16x8 whi[PP][2], wlo[PP][2];
    float bias[PP], slope[PP], bet[PP];
#pragma unroll
    for (int p = 0; p < PP; p++) {
#pragma unroll
        for (int kk = 0; kk < 2; kk++)
            split8(Wg + p * 4096 + colg * 64 + kk * 32 + q * 8, true, whi[p][kk], wlo[p][kk]);
        bias[p] = b[p * 64 + colg];
        slope[p] = a[p];
        bet[p] = beta[p];
    }
    int rt = blockIdx.x;
    bf16x8 ah[2], al[2];
    if (rt < ntiles) {
        size_t rb = (size_t)(rt * 16 + nl) * 64 + q * 8;
#pragma unroll
        for (int kk = 0; kk < 2; kk++) {
            ah[kk] = *(const bf16x8*)(Xhi + rb + kk * 32);
            al[kk] = *(const bf16x8*)(Xlo + rb + kk * 32);
        }
    }
    for (; rt < ntiles; rt += gridDim.x) {
        int rn = rt + gridDim.x;
        bf16x8 pfh[2], pfl[2];
        if (rn < ntiles) {
            size_t rb = (size_t)(rn * 16 + nl) * 64 + q * 8;
#pragma unroll
            for (int kk = 0; kk < 2; kk++) {
                pfh[kk] = *(const bf16x8*)(Xhi + rb + kk * 32);
                pfl[kk] = *(const bf16x8*)(Xlo + rb + kk * 32);
            }
        }
        float mix[4] = {0.f, 0.f, 0.f, 0.f};
#pragma unroll
        for (int p = 0; p < PP; p++) {
            f32x4 acc = {0.f, 0.f, 0.f, 0.f};
            acc = __builtin_amdgcn_mfma_f32_16x16x32_bf16(ah[0], whi[p][0], acc, 0, 0, 0);
            acc = __builtin_amdgcn_mfma_f32_16x16x32_bf16(ah[1], whi[p][1], acc, 0, 0, 0);
            acc = __builtin_amdgcn_mfma_f32_16x16x32_bf16(al[0], whi[p][0], acc, 0, 0, 0);
            acc = __builtin_amdgcn_mfma_f32_16x16x32_bf16(al[1], whi[p][1], acc, 0, 0, 0);
            acc = __builtin_amdgcn_mfma_f32_16x16x32_bf16(ah[0], wlo[p][0], acc, 0, 0, 0);
            acc = __builtin_amdgcn_mfma_f32_16x16x32_bf16(ah[1], wlo[p][1], acc, 0, 0, 0);
            acc = __builtin_amdgcn_mfma_f32_16x16x32_bf16(al[0], wlo[p][0], acc, 0, 0, 0);
            acc = __builtin_amdgcn_mfma_f32_16x16x32_bf16(al[1], wlo[p][1], acc, 0, 0, 0);
#pragma unroll
            for (int i = 0; i < 4; i++) {
                float o = acc[i] + bias[p];
                o = (o > 0.f) ? o : slope[p] * o;
                mix[i] = fmaf(bet[p], o, mix[i]);
            }
        }
#pragma unroll
        for (int i = 0; i < 4; i++) {
            int r = rt * 16 + q * 4 + i;
            if (r < n) {
                size_t idx = (size_t)r * 64 + colg;
                out[idx] = accum ? (out[idx] + mix[i]) : mix[i];
            }
        }
#pragma unroll
        for (int kk = 0; kk < 2; kk++) {
            ah[kk] = pfh[kk];
            al[kk] = pfl[kk];
        }
    }
}

__global__ __launch_bounds__(64) void compute_beta(const float* __restrict__ s_sums,
                                                   const float* __restrict__ att, int n, int P,
                                                   float* __restrict__ beta) {
    int lane = threadIdx.x;
    float av = att[lane];
    float l[8];
    for (int p = 0; p < P; p++) l[p] = s_sums[p * 64 + lane] * av;
#pragma unroll
    for (int off = 32; off > 0; off >>= 1)
        for (int p = 0; p < 8; p++)
            if (p < P) l[p] += __shfl_down(l[p], off);
    if (lane == 0) {
        const float inv = 1.0f / (float)n;
        float m = -1e30f;
        for (int p = 0; p < P; p++) {
            l[p] *= inv;
            m = fmaxf(m, l[p]);
        }
        float s = 0.f;
        for (int p = 0; p < P; p++) {
            l[p] = __expf(l[p] - m);
            s += l[p];
        }
        for (int p = 0; p < P; p++) beta[p] = l[p] / s;
    }
}

// ---------------- driver ----------------

extern "C" void kernel_launch(void* const* d_in, const int* in_sizes, int n_in,
                              void* d_out, int out_size, void* d_ws, size_t ws_size,
                              hipStream_t stream) {
    const float* h = (const float*)d_in[0];
    const float* W = (const float*)d_in[1];
    const float* b = (const float*)d_in[2];
    const float* a = (const float*)d_in[3];
    const float* fc_w = (const float*)d_in[4];
    const float* fc_b = (const float*)d_in[5];
    const float* att = (const float*)d_in[6];
    const float* adj = (const float*)d_in[7];
    const void* row = d_in[8];
    const void* col = d_in[9];
    const void* mask1 = d_in[10];
    const void* mask2 = d_in[11];
    float* out = (float*)d_out;

    int P = in_sizes[3];
    if (P < 1 || P > 8) P = 3;
    int N = in_sizes[0] / 64;
    int E = in_sizes[7];
    int N16 = (N + 15) & ~15;
    int ntiles = N16 >> 4;

    // bucket geometry: rows/bucket = 1<<shift, buckets <= 2048
    int shift = 8;
    while (((N >> shift) + 1) > 2048) shift++;
    int NB = (N >> shift) + 1;

    char* w = (char*)d_ws;
    auto alloc = [&](size_t bytes) {
        void* p = (void*)w;
        w += (bytes + 255) & ~(size_t)255;
        return p;
    };
    int* row_ptr = (int*)alloc((size_t)(N + 1) * 4);
    int* col_s = (int*)alloc((size_t)E * 4);
    float* val_s = (float*)alloc((size_t)E * 4);
    int* bptr = (int*)alloc((size_t)(NB + 1) * 4);
    int* bcur = (int*)alloc((size_t)NB * 4);
    int2* rcbin = (int2*)alloc((size_t)E * 8);
    float* valbin = (float*)alloc((size_t)E * 4);
    unsigned char* m1c = (unsigned char*)alloc(N);
    unsigned char* m2c = (unsigned char*)alloc(N);
    short* axm_hi = (short*)alloc((size_t)N16 * 64 * 2);
    short* axm_lo = (short*)alloc((size_t)N16 * 64 * 2);
    short* axf_hi = (short*)alloc((size_t)N16 * 64 * 2);
    short* axf_lo = (short*)alloc((size_t)N16 * 64 * 2);
    float* s_sums = (float*)alloc(8 * 64 * 4);
    float* beta = (float*)alloc(8 * 4);
    int* flags = (int*)alloc(256);

    int nw_mask = N / 4 > 25000 ? 25000 : N / 4;
    int nw_idx = E / 4 > 25000 ? 25000 : E / 4;
    forensic_kernel<<<1, 256, 0, stream>>>((const unsigned int*)mask1, (const unsigned int*)row,
                                           nw_mask, nw_idx, flags);
    conv_masks<<<(N + 255) / 256, 256, 0, stream>>>(mask1, mask2, flags, N, m1c, m2c);

    hipMemsetAsync(bptr, 0, (size_t)(NB + 1) * 4, stream);
    if (N16 > N) {  // zero pad rows so tail-tile fragment loads need no predicate
        size_t padoff = (size_t)N * 64, padbytes = (size_t)(N16 - N) * 64 * 2;
        hipMemsetAsync(axm_hi + padoff, 0, padbytes, stream);
        hipMemsetAsync(axm_lo + padoff, 0, padbytes, stream);
        hipMemsetAsync(axf_hi + padoff, 0, padbytes, stream);
        hipMemsetAsync(axf_lo + padoff, 0, padbytes, stream);
    }
    bucket_hist<<<1024, 256, 0, stream>>>(row, flags, E, N, shift, NB, bptr);
    bucket_scan<<<1, 1024, 0, stream>>>(bptr, NB, bcur, N, row_ptr);
    int bin_blocks = (E + 2047) / 2048;
    bin_pass2<<<bin_blocks, 256, 0, stream>>>(row, col, adj, flags, E, N, shift, NB, bcur, rcbin,
                                              valbin);
    csr_finalize<<<NB, 512, 0, stream>>>(bptr, rcbin, valbin, N, shift, row_ptr, col_s, val_s);

    int spmm_grid = ((size_t)N * 64 + 255) / 256;  // one wave per row
    int tanh_blocks = 1024;
    int mix_blocks = 1024;

    // tail: ax planes -> [A: embed GEMM + fc + tanh-sum] -> beta -> [B: recompute + mix]
    auto tail = [&](const short* axhi, const short* axlo, float* dst) {
        hipMemsetAsync(s_sums, 0, 8 * 64 * 4, stream);
        if (P == 3) {
            gemm_tanh<3><<<tanh_blocks, 256, 0, stream>>>(axhi, axlo, W, b, a, fc_w, fc_b, N,
                                                          ntiles, s_sums);
        } else {
            for (int p = 0; p < P; p++)
                gemm_tanh<1><<<tanh_blocks, 256, 0, stream>>>(axhi, axlo, W + p * 4096,
                                                              b + p * 64, a + p, fc_w, fc_b, N,
                                                              ntiles, s_sums + p * 64);
        }
        compute_beta<<<1, 64, 0, stream>>>(s_sums, att, N, P, beta);
        if (P == 3) {
            gemm_mix<3><<<mix_blocks, 256, 0, stream>>>(axhi, axlo, W, b, a, beta, N, ntiles, dst,
                                                        0);
        } else {
            for (int p = 0; p < P; p++)
                gemm_mix<1><<<mix_blocks, 256, 0, stream>>>(axhi, axlo, W + p * 4096, b + p * 64,
                                                            a + p, beta + p, N, ntiles, dst,
                                                            p != 0);
        }
    };

    // pass 0 + 1 share one edge sweep: ax_masked and ax_full from a single gather
    spmm_dual<<<spmm_grid, 256, 0, stream>>>(h, row_ptr, col_s, val_s, m1c, N, axm_hi, axm_lo,
                                             axf_hi, axf_lo);
    tail(axm_hi, axm_lo, out);                  // z_mp
    tail(axf_hi, axf_lo, out + (size_t)N * 64); // z_mp2
    // pass 2 decodes from z_mp (in d_out), masked by mask2 (gather skipped when masked)
    spmm_one<<<spmm_grid, 256, 0, stream>>>(out, row_ptr, col_s, val_s, m2c, N, axm_hi, axm_lo);
    tail(axm_hi, axm_lo, out + (size_t)2 * N * 64);  // x_recon
}

// Round 8
// 563.973 us; speedup vs baseline: 1.1789x; 1.0483x over previous
//
#include <hip/hip_runtime.h>
#include <hip/hip_bf16.h>

typedef __hip_bfloat16 bf16;
typedef __attribute__((ext_vector_type(8))) short bf16x8;  // 8 bf16 in 4 VGPRs
typedef __attribute__((ext_vector_type(4))) float f32x4;

// ---------------- bf16 split helpers (Ootomo bf16x3 scheme) ----------------

__device__ __forceinline__ short f2bf(float x) {  // RNE float->bf16 bits
    unsigned u = __float_as_uint(x);
    unsigned r = (u + 0x7FFFu + ((u >> 16) & 1u)) >> 16;
    return (short)r;
}
__device__ __forceinline__ float bf2f(short s) {
    return __uint_as_float(((unsigned)(unsigned short)s) << 16);
}
__device__ __forceinline__ void split1(float v, short& h, short& l) {
    h = f2bf(v);
    l = f2bf(v - bf2f(h));
}

// Load 8 consecutive floats (16B-aligned), split into hi/lo bf16 fragments.
__device__ __forceinline__ void split8(const float* __restrict__ p, bool ok, bf16x8& hi,
                                       bf16x8& lo) {
    float v[8];
    if (ok) {
        float4 x0 = ((const float4*)p)[0];
        float4 x1 = ((const float4*)p)[1];
        v[0] = x0.x; v[1] = x0.y; v[2] = x0.z; v[3] = x0.w;
        v[4] = x1.x; v[5] = x1.y; v[6] = x1.z; v[7] = x1.w;
    } else {
#pragma unroll
        for (int j = 0; j < 8; j++) v[j] = 0.f;
    }
#pragma unroll
    for (int j = 0; j < 8; j++) {
        short hb = f2bf(v[j]);
        hi[j] = hb;
        lo[j] = f2bf(v[j] - bf2f(hb));
    }
}

__device__ __forceinline__ float fast_tanh(float x) {
    x = fminf(fmaxf(x, -15.f), 15.f);
    float t = __expf(2.f * x);
    return __fdividef(t - 1.f, t + 1.f);
}

__device__ __forceinline__ void fma4(float4& acc, float v, const float4& x) {
    acc.x = fmaf(v, x.x, acc.x);
    acc.y = fmaf(v, x.y, acc.y);
    acc.z = fmaf(v, x.z, acc.z);
    acc.w = fmaf(v, x.w, acc.w);
}

__device__ __forceinline__ void red4(float4& a) {
    a.x += __shfl_xor(a.x, 16); a.y += __shfl_xor(a.y, 16);
    a.z += __shfl_xor(a.z, 16); a.w += __shfl_xor(a.w, 16);
    a.x += __shfl_xor(a.x, 32); a.y += __shfl_xor(a.y, 32);
    a.z += __shfl_xor(a.z, 32); a.w += __shfl_xor(a.w, 32);
}

// ---------------- dtype forensics (masks / indices) ----------------
// modes: 0=u8/bool, 1=int32, 2=float32, 3=int64, 4=float64
__global__ __launch_bounds__(256) void forensic_kernel(const unsigned int* __restrict__ mask_w,
                                                       const unsigned int* __restrict__ idx_w,
                                                       int nw_mask, int nw_idx,
                                                       int* __restrict__ flags) {
    __shared__ int sm[6];
    int t = threadIdx.x;
    if (t < 6) sm[t] = 0;
    __syncthreads();
    int m_gt1 = 0, m_f32 = 0, m_f64 = 0, m_oddnz = 0, i_hi = 0, i_oddnz = 0;
    for (int i = t; i < nw_mask; i += 256) {
        unsigned int w = mask_w[i];
        if (w > 1u && w != 0x3F800000u && w != 0x3FF00000u) m_gt1++;
        if (w == 0x3F800000u) m_f32++;
        if ((i & 1) && w == 0x3FF00000u) m_f64++;
        if ((i & 1) && w != 0u) m_oddnz++;
    }
    for (int i = t; i < nw_idx; i += 256) {
        unsigned int v = idx_w[i];
        if (v >= 0x20000000u) i_hi++;
        if ((i & 1) && v != 0u) i_oddnz++;
    }
    atomicAdd(&sm[0], m_gt1);
    atomicAdd(&sm[1], m_f32);
    atomicAdd(&sm[2], m_f64);
    atomicAdd(&sm[3], m_oddnz);
    atomicAdd(&sm[4], i_hi);
    atomicAdd(&sm[5], i_oddnz);
    __syncthreads();
    if (t == 0) {
        int mmode;
        if (sm[1] > 50) mmode = 2;
        else if (sm[2] > 50) mmode = 4;
        else if (sm[0] > 50) mmode = 0;
        else if (sm[3] > 50) mmode = 1;
        else mmode = 3;
        int imode;
        if (sm[4] > (nw_idx * 3) / 4) imode = 2;
        else if (sm[4] > nw_idx / 4) imode = 4;
        else if (sm[5] > 50) imode = 1;
        else imode = 3;
        flags[0] = mmode;
        flags[1] = imode;
    }
}

__device__ __forceinline__ int fetch_idx(const void* p, int e, int mode) {
    switch (mode) {
        case 1: return ((const int*)p)[e];
        case 3: return (int)(((const long long*)p)[e]);
        case 2: return (int)(((const float*)p)[e]);
        default: return (int)(((const double*)p)[e]);
    }
}

__device__ __forceinline__ bool conv_one(const void* m, int mode, int i) {
    switch (mode) {
        case 0: return ((const unsigned char*)m)[i] != 0;
        case 1: return ((const int*)m)[i] != 0;
        case 2: return ((const float*)m)[i] != 0.f;
        case 3: return ((const long long*)m)[i] != 0;
        default: return ((const double*)m)[i] != 0.0;
    }
}

// Both masks in one launch.
__global__ __launch_bounds__(256) void conv_masks(const void* __restrict__ m1,
                                                  const void* __restrict__ m2,
                                                  const int* __restrict__ flags, int n,
                                                  unsigned char* __restrict__ o1,
                                                  unsigned char* __restrict__ o2) {
    int mode = flags[0];
    int i = blockIdx.x * 256 + threadIdx.x;
    if (i >= n) return;
    o1[i] = conv_one(m1, mode, i) ? 1 : 0;
    o2[i] = conv_one(m2, mode, i) ? 1 : 0;
}

// ---------------- CSR build: two-level bucket sort, block-aggregated binning --------

__global__ __launch_bounds__(256) void bucket_hist(const void* __restrict__ row,
                                                   const int* __restrict__ flags, int e_cnt,
                                                   int n, int shift, int nb,
                                                   int* __restrict__ bcnt) {
    __shared__ int hist[2048];
    int t = threadIdx.x;
    for (int i = t; i < nb; i += 256) hist[i] = 0;
    __syncthreads();
    int imode = flags[1];
    for (int e = blockIdx.x * 256 + t; e < e_cnt; e += gridDim.x * 256) {
        int r = fetch_idx(row, e, imode);
        if ((unsigned)r < (unsigned)n) atomicAdd(&hist[r >> shift], 1);
    }
    __syncthreads();
    for (int i = t; i < nb; i += 256)
        if (hist[i]) atomicAdd(&bcnt[i], hist[i]);
}

// bptr: in = counts, out = exclusive offsets; also fills bcur and row_ptr[n].
__global__ __launch_bounds__(1024) void bucket_scan(int* __restrict__ bptr, int nb,
                                                    int* __restrict__ bcur, int n,
                                                    int* __restrict__ row_ptr) {
    __shared__ int sh[1024];
    int t = threadIdx.x;
    int i0 = t * 2, i1 = t * 2 + 1;
    int a = (i0 < nb) ? bptr[i0] : 0;
    int b = (i1 < nb) ? bptr[i1] : 0;
    int s = a + b;
    sh[t] = s;
    __syncthreads();
    for (int off = 1; off < 1024; off <<= 1) {
        int u = (t >= off) ? sh[t - off] : 0;
        __syncthreads();
        sh[t] += u;
        __syncthreads();
    }
    int base = sh[t] - s;  // exclusive prefix
    if (i0 < nb) { bptr[i0] = base; bcur[i0] = base; }
    if (i1 < nb) { bptr[i1] = base + a; bcur[i1] = base + a; }
    if (t == 1023) {
        bptr[nb] = sh[1023];
        row_ptr[n] = sh[1023];
    }
}

// Block-aggregated binning; 2048 edges/block, register-cached.
__global__ __launch_bounds__(256) void bin_pass2(const void* __restrict__ row,
                                                 const void* __restrict__ col,
                                                 const float* __restrict__ vals,
                                                 const int* __restrict__ flags, int e_cnt, int n,
                                                 int shift, int nb, int* __restrict__ bcur,
                                                 int2* __restrict__ rcbin,
                                                 float* __restrict__ valbin) {
    __shared__ int hist[2048];
    __shared__ int base[2048];
    int t = threadIdx.x;
    int e0 = blockIdx.x * 2048;
    if (e0 >= e_cnt) return;
    int imode = flags[1];
    for (int i = t; i < nb; i += 256) hist[i] = 0;
    __syncthreads();
    // phase 1: load this thread's 8 edges into registers + LDS histogram
    int rr[8], cc[8];
    float vv[8];
    bool ok[8];
#pragma unroll
    for (int j = 0; j < 8; j++) {
        int e = e0 + j * 256 + t;
        ok[j] = false;
        if (e < e_cnt) {
            int r = fetch_idx(row, e, imode);
            if ((unsigned)r < (unsigned)n) {
                ok[j] = true;
                rr[j] = r;
                int c = fetch_idx(col, e, imode);
                cc[j] = ((unsigned)c < (unsigned)n) ? c : 0;
                vv[j] = vals[e];
                atomicAdd(&hist[r >> shift], 1);
            }
        }
    }
    __syncthreads();
    // phase 2: reserve one contiguous range per bucket (1 global atomic each)
    for (int i = t; i < nb; i += 256) {
        int c = hist[i];
        base[i] = c ? atomicAdd(&bcur[i], c) : 0;
        hist[i] = 0;  // reuse as within-block cursor
    }
    __syncthreads();
    // phase 3: scatter from registers into reserved ranges
#pragma unroll
    for (int j = 0; j < 8; j++) {
        if (ok[j]) {
            int bk = rr[j] >> shift;
            int pos = base[bk] + atomicAdd(&hist[bk], 1);
            rcbin[pos] = make_int2(rr[j], cc[j]);
            valbin[pos] = vv[j];
        }
    }
}

// One block per bucket, 512 threads. rows-per-bucket <= 1024.
__global__ __launch_bounds__(512) void csr_finalize(const int* __restrict__ bptr,
                                                    const int2* __restrict__ rcbin,
                                                    const float* __restrict__ valbin, int n,
                                                    int shift, int* __restrict__ row_ptr,
                                                    int* __restrict__ col_s,
                                                    float* __restrict__ val_s) {
    __shared__ int cnt[1024];
    __shared__ int curs[1024];
    __shared__ int red[512];
    int b = blockIdx.x, t = threadIdx.x;
    int rpb = 1 << shift;
    int r0 = b << shift;
    int rows = n - r0;
    if (rows <= 0) return;
    if (rows > rpb) rows = rpb;
    int ebase = bptr[b], eend = bptr[b + 1];
    for (int i = t; i < rows; i += 512) cnt[i] = 0;
    __syncthreads();
    for (int e = ebase + t; e < eend; e += 512) atomicAdd(&cnt[rcbin[e].x - r0], 1);
    __syncthreads();
    // exclusive scan of cnt[0..rows): 2 values per thread + block scan
    int v[2], s = 0;
#pragma unroll
    for (int j = 0; j < 2; j++) {
        int idx = t * 2 + j;
        v[j] = (idx < rows) ? cnt[idx] : 0;
        s += v[j];
    }
    red[t] = s;
    __syncthreads();
    for (int off = 1; off < 512; off <<= 1) {
        int u = (t >= off) ? red[t - off] : 0;
        __syncthreads();
        red[t] += u;
        __syncthreads();
    }
    int run = ebase + red[t] - s;
#pragma unroll
    for (int j = 0; j < 2; j++) {
        int idx = t * 2 + j;
        if (idx < rows) {
            row_ptr[r0 + idx] = run;
            curs[idx] = run;
            run += v[j];
        }
    }
    __syncthreads();
    for (int e = ebase + t; e < eend; e += 512) {
        int2 rc = rcbin[e];
        float vv = valbin[e];
        int pos = atomicAdd(&curs[rc.x - r0], 1);
        col_s[pos] = rc.y;
        val_s[pos] = vv;
    }
}

// ---------------- SpMM: ax = A @ x  (CSR) ----------------
// Round-8: TWO adjacent rows per wave. Round-7 counters (HBM 43%, VALU 45%,
// occ 75%) showed per-wave latency chains, not bandwidth: one ~1500-cycle
// serial chain (row_ptr -> col -> mask -> shfl -> gather) per wave. Two rows
// give 8 gathers in flight, overlap two prologue chains, share CSR cache
// lines (adjacent ranges), and halve the grid. Outputs stay pre-split bf16
// planes; the 4 stores go to the 4 lane-groups in parallel.

__device__ __forceinline__ void store_split4(short* __restrict__ hi, short* __restrict__ lo,
                                             size_t o, const float4& v) {
    short4 h4, l4;
    split1(v.x, h4.x, l4.x); split1(v.y, h4.y, l4.y);
    split1(v.z, h4.z, l4.z); split1(v.w, h4.w, l4.w);
    *(short4*)(hi + o) = h4;
    *(short4*)(lo + o) = l4;
}

__global__ __launch_bounds__(256) void spmm_dual(const float* __restrict__ X,
                                                 const int* __restrict__ row_ptr,
                                                 const int* __restrict__ col_s,
                                                 const float* __restrict__ val_s,
                                                 const unsigned char* __restrict__ mask, int n,
                                                 short* __restrict__ axm_hi,
                                                 short* __restrict__ axm_lo,
                                                 short* __restrict__ axf_hi,
                                                 short* __restrict__ axf_lo) {
    int gid = blockIdx.x * 256 + threadIdx.x;
    int wv = gid >> 6;
    int r0 = wv * 2;
    if (r0 >= n) return;
    int lane = threadIdx.x & 63;
    int g = lane >> 4, sub = lane & 15;
    int r1 = r0 + 1;
    bool has1 = r1 < n;
    int s0 = row_ptr[r0];
    int e0 = row_ptr[r0 + 1];
    int e1 = has1 ? row_ptr[r0 + 2] : e0;
    int s1 = e0;
    int cnt0 = e0 - s0, cnt1 = e1 - s1;
    int myc0 = 0, myc1 = 0;
    float myf0 = 0.f, mym0 = 0.f, myf1 = 0.f, mym1 = 0.f;
    if (lane < cnt0) {
        myc0 = col_s[s0 + lane];
        float v = val_s[s0 + lane];
        myf0 = v;
        mym0 = mask[myc0] ? 0.f : v;
    }
    if (lane < cnt1) {
        myc1 = col_s[s1 + lane];
        float v = val_s[s1 + lane];
        myf1 = v;
        mym1 = mask[myc1] ? 0.f : v;
    }
    int cm0 = cnt0 > 64 ? 64 : cnt0;
    int cm1 = cnt1 > 64 ? 64 : cnt1;
    int cm = cm0 > cm1 ? cm0 : cm1;
    float4 f0a = {0, 0, 0, 0}, f0b = {0, 0, 0, 0}, m0a = {0, 0, 0, 0}, m0b = {0, 0, 0, 0};
    float4 f1a = {0, 0, 0, 0}, f1b = {0, 0, 0, 0}, m1a = {0, 0, 0, 0}, m1b = {0, 0, 0, 0};
    for (int i = 0; i < cm; i += 8) {
        int iA = i + g, iB = i + 4 + g;
        // row0
        int cA0 = __shfl(myc0, iA), cB0 = __shfl(myc0, iB);
        float fA0 = __shfl(myf0, iA), fB0 = __shfl(myf0, iB);
        float mA0 = __shfl(mym0, iA), mB0 = __shfl(mym0, iB);
        // row1
        int cA1 = __shfl(myc1, iA), cB1 = __shfl(myc1, iB);
        float fA1 = __shfl(myf1, iA), fB1 = __shfl(myf1, iB);
        float mA1 = __shfl(mym1, iA), mB1 = __shfl(mym1, iB);
        if (iA < cm0) {
            float4 x = *(const float4*)(X + (size_t)cA0 * 64 + sub * 4);
            fma4(f0a, fA0, x);
            fma4(m0a, mA0, x);
        }
        if (iA < cm1) {
            float4 x = *(const float4*)(X + (size_t)cA1 * 64 + sub * 4);
            fma4(f1a, fA1, x);
            fma4(m1a, mA1, x);
        }
        if (iB < cm0) {
            float4 x = *(const float4*)(X + (size_t)cB0 * 64 + sub * 4);
            fma4(f0b, fB0, x);
            fma4(m0b, mB0, x);
        }
        if (iB < cm1) {
            float4 x = *(const float4*)(X + (size_t)cB1 * 64 + sub * 4);
            fma4(f1b, fB1, x);
            fma4(m1b, mB1, x);
        }
    }
    for (int i = 64 + g; i < cnt0; i += 4) {  // rare overflow rows
        int c = col_s[s0 + i];
        float v = val_s[s0 + i];
        float vm = mask[c] ? 0.f : v;
        float4 x = *(const float4*)(X + (size_t)c * 64 + sub * 4);
        fma4(f0a, v, x);
        fma4(m0a, vm, x);
    }
    for (int i = 64 + g; i < cnt1; i += 4) {
        int c = col_s[s1 + i];
        float v = val_s[s1 + i];
        float vm = mask[c] ? 0.f : v;
        float4 x = *(const float4*)(X + (size_t)c * 64 + sub * 4);
        fma4(f1a, v, x);
        fma4(m1a, vm, x);
    }
    f0a.x += f0b.x; f0a.y += f0b.y; f0a.z += f0b.z; f0a.w += f0b.w;
    m0a.x += m0b.x; m0a.y += m0b.y; m0a.z += m0b.z; m0a.w += m0b.w;
    f1a.x += f1b.x; f1a.y += f1b.y; f1a.z += f1b.z; f1a.w += f1b.w;
    m1a.x += m1b.x; m1a.y += m1b.y; m1a.z += m1b.z; m1a.w += m1b.w;
    red4(f0a);
    red4(m0a);
    red4(f1a);
    red4(m1a);
    size_t o0 = (size_t)r0 * 64 + sub * 4;
    size_t o1 = (size_t)r1 * 64 + sub * 4;
    if (g == 0) store_split4(axf_hi, axf_lo, o0, f0a);
    else if (g == 1) store_split4(axm_hi, axm_lo, o0, m0a);
    else if (g == 2 && has1) store_split4(axf_hi, axf_lo, o1, f1a);
    else if (g == 3 && has1) store_split4(axm_hi, axm_lo, o1, m1a);
}

// Single-output masked SpMM; masked edges skip the gather; two rows per wave.
__global__ __launch_bounds__(256) void spmm_one(const float* __restrict__ X,
                                                const int* __restrict__ row_ptr,
                                                const int* __restrict__ col_s,
                                                const float* __restrict__ val_s,
                                                const unsigned char* __restrict__ mask, int n,
                                                short* __restrict__ ax_hi,
                                                short* __restrict__ ax_lo) {
    int gid = blockIdx.x * 256 + threadIdx.x;
    int wv = gid >> 6;
    int r0 = wv * 2;
    if (r0 >= n) return;
    int lane = threadIdx.x & 63;
    int g = lane >> 4, sub = lane & 15;
    int r1 = r0 + 1;
    bool has1 = r1 < n;
    int s0 = row_ptr[r0];
    int e0 = row_ptr[r0 + 1];
    int e1 = has1 ? row_ptr[r0 + 2] : e0;
    int s1 = e0;
    int cnt0 = e0 - s0, cnt1 = e1 - s1;
    int myc0 = 0, myc1 = 0;
    float myv0 = 0.f, myv1 = 0.f;
    if (lane < cnt0) {
        myc0 = col_s[s0 + lane];
        float v = val_s[s0 + lane];
        myv0 = mask[myc0] ? 0.f : v;
    }
    if (lane < cnt1) {
        myc1 = col_s[s1 + lane];
        float v = val_s[s1 + lane];
        myv1 = mask[myc1] ? 0.f : v;
    }
    int cm0 = cnt0 > 64 ? 64 : cnt0;
    int cm1 = cnt1 > 64 ? 64 : cnt1;
    int cm = cm0 > cm1 ? cm0 : cm1;
    float4 a0a = {0, 0, 0, 0}, a0b = {0, 0, 0, 0};
    float4 a1a = {0, 0, 0, 0}, a1b = {0, 0, 0, 0};
    for (int i = 0; i < cm; i += 8) {
        int iA = i + g, iB = i + 4 + g;
        int cA0 = __shfl(myc0, iA), cB0 = __shfl(myc0, iB);
        float vA0 = __shfl(myv0, iA), vB0 = __shfl(myv0, iB);
        int cA1 = __shfl(myc1, iA), cB1 = __shfl(myc1, iB);
        float vA1 = __shfl(myv1, iA), vB1 = __shfl(myv1, iB);
        if (iA < cm0 && vA0 != 0.f) {
            float4 x = *(const float4*)(X + (size_t)cA0 * 64 + sub * 4);
            fma4(a0a, vA0, x);
        }
        if (iA < cm1 && vA1 != 0.f) {
            float4 x = *(const float4*)(X + (size_t)cA1 * 64 + sub * 4);
            fma4(a1a, vA1, x);
        }
        if (iB < cm0 && vB0 != 0.f) {
            float4 x = *(const float4*)(X + (size_t)cB0 * 64 + sub * 4);
            fma4(a0b, vB0, x);
        }
        if (iB < cm1 && vB1 != 0.f) {
            float4 x = *(const float4*)(X + (size_t)cB1 * 64 + sub * 4);
            fma4(a1b, vB1, x);
        }
    }
    for (int i = 64 + g; i < cnt0; i += 4) {
        int c = col_s[s0 + i];
        if (mask[c]) continue;
        float v = val_s[s0 + i];
        float4 x = *(const float4*)(X + (size_t)c * 64 + sub * 4);
        fma4(a0a, v, x);
    }
    for (int i = 64 + g; i < cnt1; i += 4) {
        int c = col_s[s1 + i];
        if (mask[c]) continue;
        float v = val_s[s1 + i];
        float4 x = *(const float4*)(X + (size_t)c * 64 + sub * 4);
        fma4(a1a, v, x);
    }
    a0a.x += a0b.x; a0a.y += a0b.y; a0a.z += a0b.z; a0a.w += a0b.w;
    a1a.x += a1b.x; a1a.y += a1b.y; a1a.z += a1b.z; a1a.w += a1b.w;
    red4(a0a);
    red4(a1a);
    size_t o0 = (size_t)r0 * 64 + sub * 4;
    size_t o1 = (size_t)r1 * 64 + sub * 4;
    if (g == 0) store_split4(ax_hi, ax_lo, o0, a0a);
    else if (g == 1 && has1) store_split4(ax_hi, ax_lo, o1, a1a);
}

// ---------------- fused kernel A: embed GEMM -> LDS bf16 planes -> fc GEMM -> tanh-sum ----
// blockIdx.y selects plane-set {0,1} (merged pass0/pass1 tails); s_sums offset
// by set*512. A-fragments direct from pre-split global planes + prefetch.

template <int PP>
__global__ __launch_bounds__(256) void gemm_tanh(const short* __restrict__ Xhi0,
                                                 const short* __restrict__ Xlo0,
                                                 const short* __restrict__ Xhi1,
                                                 const short* __restrict__ Xlo1,
                                                 const float* __restrict__ Wg,
                                                 const float* __restrict__ b,
                                                 const float* __restrict__ a,
                                                 const float* __restrict__ fcw,
                                                 const float* __restrict__ fcb, int n, int ntiles,
                                                 float* __restrict__ s_sums) {
    __shared__ __align__(16) short ehi[PP][16][72], elo[PP][16][72];
    int set = blockIdx.y;
    const short* __restrict__ Xhi = set ? Xhi1 : Xhi0;
    const short* __restrict__ Xlo = set ? Xlo1 : Xlo0;
    float* __restrict__ ss = s_sums + set * 512;
    int t = threadIdx.x;
    int wv = t >> 6, lane = t & 63, nl = lane & 15, q = lane >> 4;
    int colg = wv * 16 + nl;
    bf16x8 whi[PP][2], wlo[PP][2];
    float bias[PP], slope[PP];
#pragma unroll
    for (int p = 0; p < PP; p++) {
#pragma unroll
        for (int kk = 0; kk < 2; kk++)
            split8(Wg + p * 4096 + colg * 64 + kk * 32 + q * 8, true, whi[p][kk], wlo[p][kk]);
        bias[p] = b[p * 64 + colg];
        slope[p] = a[p];
    }
    bf16x8 fhi[2], flo[2];
#pragma unroll
    for (int kk = 0; kk < 2; kk++)
        split8(fcw + colg * 64 + kk * 32 + q * 8, true, fhi[kk], flo[kk]);
    float fbias = fcb[colg];
    float ssum[PP];
#pragma unroll
    for (int p = 0; p < PP; p++) ssum[p] = 0.f;

    int rt = blockIdx.x;
    bf16x8 ah[2], al[2];
    if (rt < ntiles) {
        size_t rb = (size_t)(rt * 16 + nl) * 64 + q * 8;
#pragma unroll
        for (int kk = 0; kk < 2; kk++) {
            ah[kk] = *(const bf16x8*)(Xhi + rb + kk * 32);
            al[kk] = *(const bf16x8*)(Xlo + rb + kk * 32);
        }
    }
    for (; rt < ntiles; rt += gridDim.x) {
#pragma unroll
        for (int p = 0; p < PP; p++) {
            f32x4 acc = {0.f, 0.f, 0.f, 0.f};
            acc = __builtin_amdgcn_mfma_f32_16x16x32_bf16(ah[0], whi[p][0], acc, 0, 0, 0);
            acc = __builtin_amdgcn_mfma_f32_16x16x32_bf16(ah[1], whi[p][1], acc, 0, 0, 0);
            acc = __builtin_amdgcn_mfma_f32_16x16x32_bf16(al[0], whi[p][0], acc, 0, 0, 0);
            acc = __builtin_amdgcn_mfma_f32_16x16x32_bf16(al[1], whi[p][1], acc, 0, 0, 0);
            acc = __builtin_amdgcn_mfma_f32_16x16x32_bf16(ah[0], wlo[p][0], acc, 0, 0, 0);
            acc = __builtin_amdgcn_mfma_f32_16x16x32_bf16(ah[1], wlo[p][1], acc, 0, 0, 0);
            acc = __builtin_amdgcn_mfma_f32_16x16x32_bf16(al[0], wlo[p][0], acc, 0, 0, 0);
            acc = __builtin_amdgcn_mfma_f32_16x16x32_bf16(al[1], wlo[p][1], acc, 0, 0, 0);
#pragma unroll
            for (int i = 0; i < 4; i++) {
                float o = acc[i] + bias[p];
                o = (o > 0.f) ? o : slope[p] * o;
                short hb, lb;
                split1(o, hb, lb);
                ehi[p][q * 4 + i][colg] = hb;
                elo[p][q * 4 + i][colg] = lb;
            }
        }
        // prefetch next tile's A-fragments (overlaps the fc phase below)
        int rn = rt + gridDim.x;
        bf16x8 pfh[2], pfl[2];
        if (rn < ntiles) {
            size_t rb = (size_t)(rn * 16 + nl) * 64 + q * 8;
#pragma unroll
            for (int kk = 0; kk < 2; kk++) {
                pfh[kk] = *(const bf16x8*)(Xhi + rb + kk * 32);
                pfl[kk] = *(const bf16x8*)(Xlo + rb + kk * 32);
            }
        }
        __syncthreads();
#pragma unroll
        for (int p = 0; p < PP; p++) {
            bf16x8 eh[2], el[2];
#pragma unroll
            for (int kk = 0; kk < 2; kk++) {
                eh[kk] = *(const bf16x8*)(&ehi[p][nl][kk * 32 + q * 8]);
                el[kk] = *(const bf16x8*)(&elo[p][nl][kk * 32 + q * 8]);
            }
            f32x4 acc = {0.f, 0.f, 0.f, 0.f};
            acc = __builtin_amdgcn_mfma_f32_16x16x32_bf16(eh[0], fhi[0], acc, 0, 0, 0);
            acc = __builtin_amdgcn_mfma_f32_16x16x32_bf16(eh[1], fhi[1], acc, 0, 0, 0);
            acc = __builtin_amdgcn_mfma_f32_16x16x32_bf16(el[0], fhi[0], acc, 0, 0, 0);
            acc = __builtin_amdgcn_mfma_f32_16x16x32_bf16(el[1], fhi[1], acc, 0, 0, 0);
            acc = __builtin_amdgcn_mfma_f32_16x16x32_bf16(eh[0], flo[0], acc, 0, 0, 0);
            acc = __builtin_amdgcn_mfma_f32_16x16x32_bf16(eh[1], flo[1], acc, 0, 0, 0);
#pragma unroll
            for (int i = 0; i < 4; i++) {
                int r = rt * 16 + q * 4 + i;
                if (r < n) ssum[p] += fast_tanh(acc[i] + fbias);
            }
        }
        __syncthreads();  // LDS reads done before next tile's writes
#pragma unroll
        for (int kk = 0; kk < 2; kk++) {
            ah[kk] = pfh[kk];
            al[kk] = pfl[kk];
        }
    }
#pragma unroll
    for (int p = 0; p < PP; p++) {
        float s = ssum[p];
        s += __shfl_xor(s, 16);
        s += __shfl_xor(s, 32);
        if (q == 0) atomicAdd(&ss[p * 64 + colg], s);
    }
}

// ---------------- fused kernel B: recompute embed GEMM, mix with beta, write out -----------
// blockIdx.y selects plane-set + beta set + output slice.

template <int PP>
__global__ __launch_bounds__(256) void gemm_mix(const short* __restrict__ Xhi0,
                                                const short* __restrict__ Xlo0,
                                                const short* __restrict__ Xhi1,
                                                const short* __restrict__ Xlo1,
                                                const float* __restrict__ Wg,
                                                const float* __restrict__ b,
                                                const float* __restrict__ a,
                                                const float* __restrict__ beta, int n, int ntiles,
                                                float* __restrict__ outbase, int accum) {
    int set = blockIdx.y;
    const short* __restrict__ Xhi = set ? Xhi1 : Xhi0;
    const short* __restrict__ Xlo = set ? Xlo1 : Xlo0;
    float* __restrict__ out = outbase + (size_t)set * n * 64;
    int t = threadIdx.x;
    int wv = t >> 6, lane = t & 63, nl = lane & 15, q = lane >> 4;
    int colg = wv * 16 + nl;
    bf16x8 whi[PP][2], wlo[PP][2];
    float bias[PP], slope[PP], bet[PP];
#pragma unroll
    for (int p = 0; p < PP; p++) {
#pragma unroll
        for (int kk = 0; kk < 2; kk++)
            split8(Wg + p * 4096 + colg * 64 + kk * 32 + q * 8, true, whi[p][kk], wlo[p][kk]);
        bias[p] = b[p * 64 + colg];
        slope[p] = a[p];
        bet[p] = beta[set * 8 + p];
    }
    int rt = blockIdx.x;
    bf16x8 ah[2], al[2];
    if (rt < ntiles) {
        size_t rb = (size_t)(rt * 16 + nl) * 64 + q * 8;
#pragma unroll
        for (int kk = 0; kk < 2; kk++) {
            ah[kk] = *(const bf16x8*)(Xhi + rb + kk * 32);
            al[kk] = *(const bf16x8*)(Xlo + rb + kk * 32);
        }
    }
    for (; rt < ntiles; rt += gridDim.x) {
        int rn = rt + gridDim.x;
        bf16x8 pfh[2], pfl[2];
        if (rn < ntiles) {
            size_t rb = (size_t)(rn * 16 + nl) * 64 + q * 8;
#pragma unroll
            for (int kk = 0; kk < 2; kk++) {
                pfh[kk] = *(const bf16x8*)(Xhi + rb + kk * 32);
                pfl[kk] = *(const bf16x8*)(Xlo + rb + kk * 32);
            }
        }
        float mix[4] = {0.f, 0.f, 0.f, 0.f};
#pragma unroll
        for (int p = 0; p < PP; p++) {
            f32x4 acc = {0.f, 0.f, 0.f, 0.f};
            acc = __builtin_amdgcn_mfma_f32_16x16x32_bf16(ah[0], whi[p][0], acc, 0, 0, 0);
            acc = __builtin_amdgcn_mfma_f32_16x16x32_bf16(ah[1], whi[p][1], acc, 0, 0, 0);
            acc = __builtin_amdgcn_mfma_f32_16x16x32_bf16(al[0], whi[p][0], acc, 0, 0, 0);
            acc = __builtin_amdgcn_mfma_f32_16x16x32_bf16(al[1], whi[p][1], acc, 0, 0, 0);
            acc = __builtin_amdgcn_mfma_f32_16x16x32_bf16(ah[0], wlo[p][0], acc, 0, 0, 0);
            acc = __builtin_amdgcn_mfma_f32_16x16x32_bf16(ah[1], wlo[p][1], acc, 0, 0, 0);
            acc = __builtin_amdgcn_mfma_f32_16x16x32_bf16(al[0], wlo[p][0], acc, 0, 0, 0);
            acc = __builtin_amdgcn_mfma_f32_16x16x32_bf16(al[1], wlo[p][1], acc, 0, 0, 0);
#pragma unroll
            for (int i = 0; i < 4; i++) {
                float o = acc[i] + bias[p];
                o = (o > 0.f) ? o : slope[p] * o;
                mix[i] = fmaf(bet[p], o, mix[i]);
            }
        }
#pragma unroll
        for (int i = 0; i < 4; i++) {
            int r = rt * 16 + q * 4 + i;
            if (r < n) {
                size_t idx = (size_t)r * 64 + colg;
                out[idx] = accum ? (out[idx] + mix[i]) : mix[i];
            }
        }
#pragma unroll
        for (int kk = 0; kk < 2; kk++) {
            ah[kk] = pfh[kk];
            al[kk] = pfl[kk];
        }
    }
}

// beta for nsets plane-sets in one 1-block launch.
__global__ __launch_bounds__(64) void compute_beta(const float* __restrict__ s_sums,
                                                   const float* __restrict__ att, int n, int P,
                                                   int nsets, float* __restrict__ beta) {
    int lane = threadIdx.x;
    float av = att[lane];
    for (int st = 0; st < nsets; st++) {
        const float* ss = s_sums + st * 512;
        float l[8];
        for (int p = 0; p < P; p++) l[p] = ss[p * 64 + lane] * av;
#pragma unroll
        for (int off = 32; off > 0; off >>= 1)
            for (int p = 0; p < 8; p++)
                if (p < P) l[p] += __shfl_down(l[p], off);
        if (lane == 0) {
            const float inv = 1.0f / (float)n;
            float m = -1e30f;
            for (int p = 0; p < P; p++) {
                l[p] *= inv;
                m = fmaxf(m, l[p]);
            }
            float s = 0.f;
            for (int p = 0; p < P; p++) {
                l[p] = __expf(l[p] - m);
                s += l[p];
            }
            for (int p = 0; p < P; p++) beta[st * 8 + p] = l[p] / s;
        }
    }
}

// ---------------- driver ----------------

extern "C" void kernel_launch(void* const* d_in, const int* in_sizes, int n_in,
                              void* d_out, int out_size, void* d_ws, size_t ws_size,
                              hipStream_t stream) {
    const float* h = (const float*)d_in[0];
    const float* W = (const float*)d_in[1];
    const float* b = (const float*)d_in[2];
    const float* a = (const float*)d_in[3];
    const float* fc_w = (const float*)d_in[4];
    const float* fc_b = (const float*)d_in[5];
    const float* att = (const float*)d_in[6];
    const float* adj = (const float*)d_in[7];
    const void* row = d_in[8];
    const void* col = d_in[9];
    const void* mask1 = d_in[10];
    const void* mask2 = d_in[11];
    float* out = (float*)d_out;

    int P = in_sizes[3];
    if (P < 1 || P > 8) P = 3;
    int N = in_sizes[0] / 64;
    int E = in_sizes[7];
    int N16 = (N + 15) & ~15;
    int ntiles = N16 >> 4;

    // bucket geometry: rows/bucket = 1<<shift, buckets <= 2048
    int shift = 8;
    while (((N >> shift) + 1) > 2048) shift++;
    int NB = (N >> shift) + 1;

    char* w = (char*)d_ws;
    auto alloc = [&](size_t bytes) {
        void* p = (void*)w;
        w += (bytes + 255) & ~(size_t)255;
        return p;
    };
    int* row_ptr = (int*)alloc((size_t)(N + 1) * 4);
    int* col_s = (int*)alloc((size_t)E * 4);
    float* val_s = (float*)alloc((size_t)E * 4);
    int* bptr = (int*)alloc((size_t)(NB + 1) * 4);
    int* bcur = (int*)alloc((size_t)NB * 4);
    int2* rcbin = (int2*)alloc((size_t)E * 8);
    float* valbin = (float*)alloc((size_t)E * 4);
    unsigned char* m1c = (unsigned char*)alloc(N);
    unsigned char* m2c = (unsigned char*)alloc(N);
    short* axm_hi = (short*)alloc((size_t)N16 * 64 * 2);
    short* axm_lo = (short*)alloc((size_t)N16 * 64 * 2);
    short* axf_hi = (short*)alloc((size_t)N16 * 64 * 2);
    short* axf_lo = (short*)alloc((size_t)N16 * 64 * 2);
    float* s_sums = (float*)alloc(2 * 512 * 4);
    float* beta = (float*)alloc(64 * 4);
    int* flags = (int*)alloc(256);

    int nw_mask = N / 4 > 25000 ? 25000 : N / 4;
    int nw_idx = E / 4 > 25000 ? 25000 : E / 4;
    forensic_kernel<<<1, 256, 0, stream>>>((const unsigned int*)mask1, (const unsigned int*)row,
                                           nw_mask, nw_idx, flags);
    conv_masks<<<(N + 255) / 256, 256, 0, stream>>>(mask1, mask2, flags, N, m1c, m2c);

    hipMemsetAsync(bptr, 0, (size_t)(NB + 1) * 4, stream);
    if (N16 > N) {  // zero pad rows so tail-tile fragment loads need no predicate
        size_t padoff = (size_t)N * 64, padbytes = (size_t)(N16 - N) * 64 * 2;
        hipMemsetAsync(axm_hi + padoff, 0, padbytes, stream);
        hipMemsetAsync(axm_lo + padoff, 0, padbytes, stream);
        hipMemsetAsync(axf_hi + padoff, 0, padbytes, stream);
        hipMemsetAsync(axf_lo + padoff, 0, padbytes, stream);
    }
    bucket_hist<<<1024, 256, 0, stream>>>(row, flags, E, N, shift, NB, bptr);
    bucket_scan<<<1, 1024, 0, stream>>>(bptr, NB, bcur, N, row_ptr);
    int bin_blocks = (E + 2047) / 2048;
    bin_pass2<<<bin_blocks, 256, 0, stream>>>(row, col, adj, flags, E, N, shift, NB, bcur, rcbin,
                                              valbin);
    csr_finalize<<<NB, 512, 0, stream>>>(bptr, rcbin, valbin, N, shift, row_ptr, col_s, val_s);

    // two rows per wave: waves = ceil(N/2), grid = ceil(waves*64/256)
    int spmm_grid = (int)(((size_t)((N + 1) / 2) * 64 + 255) / 256);
    int tanh_blocks = 1024;
    int mix_blocks = 1024;

    auto tail = [&](const short* xh0, const short* xl0, const short* xh1, const short* xl1,
                    int nsets, float* dst) {
        hipMemsetAsync(s_sums, 0, 2 * 512 * 4, stream);
        if (P == 3) {
            gemm_tanh<3><<<dim3(tanh_blocks, nsets), 256, 0, stream>>>(
                xh0, xl0, xh1, xl1, W, b, a, fc_w, fc_b, N, ntiles, s_sums);
        } else {
            for (int p = 0; p < P; p++)
                gemm_tanh<1><<<dim3(tanh_blocks, nsets), 256, 0, stream>>>(
                    xh0, xl0, xh1, xl1, W + p * 4096, b + p * 64, a + p, fc_w, fc_b, N, ntiles,
                    s_sums + p * 64);
        }
        compute_beta<<<1, 64, 0, stream>>>(s_sums, att, N, P, nsets, beta);
        if (P == 3) {
            gemm_mix<3><<<dim3(mix_blocks, nsets), 256, 0, stream>>>(
                xh0, xl0, xh1, xl1, W, b, a, beta, N, ntiles, dst, 0);
        } else {
            for (int p = 0; p < P; p++)
                gemm_mix<1><<<dim3(mix_blocks, nsets), 256, 0, stream>>>(
                    xh0, xl0, xh1, xl1, W + p * 4096, b + p * 64, a + p, beta + p, N, ntiles, dst,
                    p != 0);
        }
    };

    // passes 0+1: one edge sweep -> {axm, axf}; merged tails (gridDim.y = 2)
    spmm_dual<<<spmm_grid, 256, 0, stream>>>(h, row_ptr, col_s, val_s, m1c, N, axm_hi, axm_lo,
                                             axf_hi, axf_lo);
    tail(axm_hi, axm_lo, axf_hi, axf_lo, 2, out);  // z_mp, z_mp2
    // pass 2 decodes from z_mp (in d_out), masked by mask2
    spmm_one<<<spmm_grid, 256, 0, stream>>>(out, row_ptr, col_s, val_s, m2c, N, axm_hi, axm_lo);
    tail(axm_hi, axm_lo, axm_hi, axm_lo, 1, out + (size_t)2 * N * 64);  // x_recon
}

// Round 9
// 561.413 us; speedup vs baseline: 1.1842x; 1.0046x over previous
//
#include <hip/hip_runtime.h>
#include <hip/hip_bf16.h>

typedef __hip_bfloat16 bf16;
typedef __attribute__((ext_vector_type(8))) short bf16x8;  // 8 bf16 in 4 VGPRs
typedef __attribute__((ext_vector_type(4))) float f32x4;

// ---------------- bf16 split helpers (Ootomo bf16x3 scheme) ----------------

__device__ __forceinline__ short f2bf(float x) {  // RNE float->bf16 bits
    unsigned u = __float_as_uint(x);
    unsigned r = (u + 0x7FFFu + ((u >> 16) & 1u)) >> 16;
    return (short)r;
}
__device__ __forceinline__ float bf2f(short s) {
    return __uint_as_float(((unsigned)(unsigned short)s) << 16);
}
__device__ __forceinline__ void split1(float v, short& h, short& l) {
    h = f2bf(v);
    l = f2bf(v - bf2f(h));
}

// Load 8 consecutive floats (16B-aligned), split into hi/lo bf16 fragments.
__device__ __forceinline__ void split8(const float* __restrict__ p, bool ok, bf16x8& hi,
                                       bf16x8& lo) {
    float v[8];
    if (ok) {
        float4 x0 = ((const float4*)p)[0];
        float4 x1 = ((const float4*)p)[1];
        v[0] = x0.x; v[1] = x0.y; v[2] = x0.z; v[3] = x0.w;
        v[4] = x1.x; v[5] = x1.y; v[6] = x1.z; v[7] = x1.w;
    } else {
#pragma unroll
        for (int j = 0; j < 8; j++) v[j] = 0.f;
    }
#pragma unroll
    for (int j = 0; j < 8; j++) {
        short hb = f2bf(v[j]);
        hi[j] = hb;
        lo[j] = f2bf(v[j] - bf2f(hb));
    }
}

__device__ __forceinline__ float fast_tanh(float x) {
    x = fminf(fmaxf(x, -15.f), 15.f);
    float t = __expf(2.f * x);
    return __fdividef(t - 1.f, t + 1.f);
}

__device__ __forceinline__ void fma4(float4& acc, float v, const float4& x) {
    acc.x = fmaf(v, x.x, acc.x);
    acc.y = fmaf(v, x.y, acc.y);
    acc.z = fmaf(v, x.z, acc.z);
    acc.w = fmaf(v, x.w, acc.w);
}

__device__ __forceinline__ void red4(float4& a) {
    a.x += __shfl_xor(a.x, 16); a.y += __shfl_xor(a.y, 16);
    a.z += __shfl_xor(a.z, 16); a.w += __shfl_xor(a.w, 16);
    a.x += __shfl_xor(a.x, 32); a.y += __shfl_xor(a.y, 32);
    a.z += __shfl_xor(a.z, 32); a.w += __shfl_xor(a.w, 32);
}

// ---------------- dtype forensics (masks / indices) ----------------
// modes: 0=u8/bool, 1=int32, 2=float32, 3=int64, 4=float64
__global__ __launch_bounds__(256) void forensic_kernel(const unsigned int* __restrict__ mask_w,
                                                       const unsigned int* __restrict__ idx_w,
                                                       int nw_mask, int nw_idx,
                                                       int* __restrict__ flags) {
    __shared__ int sm[6];
    int t = threadIdx.x;
    if (t < 6) sm[t] = 0;
    __syncthreads();
    int m_gt1 = 0, m_f32 = 0, m_f64 = 0, m_oddnz = 0, i_hi = 0, i_oddnz = 0;
    for (int i = t; i < nw_mask; i += 256) {
        unsigned int w = mask_w[i];
        if (w > 1u && w != 0x3F800000u && w != 0x3FF00000u) m_gt1++;
        if (w == 0x3F800000u) m_f32++;
        if ((i & 1) && w == 0x3FF00000u) m_f64++;
        if ((i & 1) && w != 0u) m_oddnz++;
    }
    for (int i = t; i < nw_idx; i += 256) {
        unsigned int v = idx_w[i];
        if (v >= 0x20000000u) i_hi++;
        if ((i & 1) && v != 0u) i_oddnz++;
    }
    atomicAdd(&sm[0], m_gt1);
    atomicAdd(&sm[1], m_f32);
    atomicAdd(&sm[2], m_f64);
    atomicAdd(&sm[3], m_oddnz);
    atomicAdd(&sm[4], i_hi);
    atomicAdd(&sm[5], i_oddnz);
    __syncthreads();
    if (t == 0) {
        int mmode;
        if (sm[1] > 50) mmode = 2;
        else if (sm[2] > 50) mmode = 4;
        else if (sm[0] > 50) mmode = 0;
        else if (sm[3] > 50) mmode = 1;
        else mmode = 3;
        int imode;
        if (sm[4] > (nw_idx * 3) / 4) imode = 2;
        else if (sm[4] > nw_idx / 4) imode = 4;
        else if (sm[5] > 50) imode = 1;
        else imode = 3;
        flags[0] = mmode;
        flags[1] = imode;
    }
}

__device__ __forceinline__ int fetch_idx(const void* p, int e, int mode) {
    switch (mode) {
        case 1: return ((const int*)p)[e];
        case 3: return (int)(((const long long*)p)[e]);
        case 2: return (int)(((const float*)p)[e]);
        default: return (int)(((const double*)p)[e]);
    }
}

__device__ __forceinline__ bool conv_one(const void* m, int mode, int i) {
    switch (mode) {
        case 0: return ((const unsigned char*)m)[i] != 0;
        case 1: return ((const int*)m)[i] != 0;
        case 2: return ((const float*)m)[i] != 0.f;
        case 3: return ((const long long*)m)[i] != 0;
        default: return ((const double*)m)[i] != 0.0;
    }
}

// Both masks in one launch.
__global__ __launch_bounds__(256) void conv_masks(const void* __restrict__ m1,
                                                  const void* __restrict__ m2,
                                                  const int* __restrict__ flags, int n,
                                                  unsigned char* __restrict__ o1,
                                                  unsigned char* __restrict__ o2) {
    int mode = flags[0];
    int i = blockIdx.x * 256 + threadIdx.x;
    if (i >= n) return;
    o1[i] = conv_one(m1, mode, i) ? 1 : 0;
    o2[i] = conv_one(m2, mode, i) ? 1 : 0;
}

// ---------------- CSR build: two-level bucket sort, block-aggregated binning --------

__global__ __launch_bounds__(256) void bucket_hist(const void* __restrict__ row,
                                                   const int* __restrict__ flags, int e_cnt,
                                                   int n, int shift, int nb,
                                                   int* __restrict__ bcnt) {
    __shared__ int hist[2048];
    int t = threadIdx.x;
    for (int i = t; i < nb; i += 256) hist[i] = 0;
    __syncthreads();
    int imode = flags[1];
    for (int e = blockIdx.x * 256 + t; e < e_cnt; e += gridDim.x * 256) {
        int r = fetch_idx(row, e, imode);
        if ((unsigned)r < (unsigned)n) atomicAdd(&hist[r >> shift], 1);
    }
    __syncthreads();
    for (int i = t; i < nb; i += 256)
        if (hist[i]) atomicAdd(&bcnt[i], hist[i]);
}

// bptr: in = counts, out = exclusive offsets; also fills bcur and row_ptr[n].
__global__ __launch_bounds__(1024) void bucket_scan(int* __restrict__ bptr, int nb,
                                                    int* __restrict__ bcur, int n,
                                                    int* __restrict__ row_ptr) {
    __shared__ int sh[1024];
    int t = threadIdx.x;
    int i0 = t * 2, i1 = t * 2 + 1;
    int a = (i0 < nb) ? bptr[i0] : 0;
    int b = (i1 < nb) ? bptr[i1] : 0;
    int s = a + b;
    sh[t] = s;
    __syncthreads();
    for (int off = 1; off < 1024; off <<= 1) {
        int u = (t >= off) ? sh[t - off] : 0;
        __syncthreads();
        sh[t] += u;
        __syncthreads();
    }
    int base = sh[t] - s;  // exclusive prefix
    if (i0 < nb) { bptr[i0] = base; bcur[i0] = base; }
    if (i1 < nb) { bptr[i1] = base + a; bcur[i1] = base + a; }
    if (t == 1023) {
        bptr[nb] = sh[1023];
        row_ptr[n] = sh[1023];
    }
}

// Block-aggregated binning; 2048 edges/block, register-cached.
__global__ __launch_bounds__(256) void bin_pass2(const void* __restrict__ row,
                                                 const void* __restrict__ col,
                                                 const float* __restrict__ vals,
                                                 const int* __restrict__ flags, int e_cnt, int n,
                                                 int shift, int nb, int* __restrict__ bcur,
                                                 int2* __restrict__ rcbin,
                                                 float* __restrict__ valbin) {
    __shared__ int hist[2048];
    __shared__ int base[2048];
    int t = threadIdx.x;
    int e0 = blockIdx.x * 2048;
    if (e0 >= e_cnt) return;
    int imode = flags[1];
    for (int i = t; i < nb; i += 256) hist[i] = 0;
    __syncthreads();
    // phase 1: load this thread's 8 edges into registers + LDS histogram
    int rr[8], cc[8];
    float vv[8];
    bool ok[8];
#pragma unroll
    for (int j = 0; j < 8; j++) {
        int e = e0 + j * 256 + t;
        ok[j] = false;
        if (e < e_cnt) {
            int r = fetch_idx(row, e, imode);
            if ((unsigned)r < (unsigned)n) {
                ok[j] = true;
                rr[j] = r;
                int c = fetch_idx(col, e, imode);
                cc[j] = ((unsigned)c < (unsigned)n) ? c : 0;
                vv[j] = vals[e];
                atomicAdd(&hist[r >> shift], 1);
            }
        }
    }
    __syncthreads();
    // phase 2: reserve one contiguous range per bucket (1 global atomic each)
    for (int i = t; i < nb; i += 256) {
        int c = hist[i];
        base[i] = c ? atomicAdd(&bcur[i], c) : 0;
        hist[i] = 0;  // reuse as within-block cursor
    }
    __syncthreads();
    // phase 3: scatter from registers into reserved ranges
#pragma unroll
    for (int j = 0; j < 8; j++) {
        if (ok[j]) {
            int bk = rr[j] >> shift;
            int pos = base[bk] + atomicAdd(&hist[bk], 1);
            rcbin[pos] = make_int2(rr[j], cc[j]);
            valbin[pos] = vv[j];
        }
    }
}

// One block per bucket, 512 threads. rows-per-bucket <= 1024.
__global__ __launch_bounds__(512) void csr_finalize(const int* __restrict__ bptr,
                                                    const int2* __restrict__ rcbin,
                                                    const float* __restrict__ valbin, int n,
                                                    int shift, int* __restrict__ row_ptr,
                                                    int* __restrict__ col_s,
                                                    float* __restrict__ val_s) {
    __shared__ int cnt[1024];
    __shared__ int curs[1024];
    __shared__ int red[512];
    int b = blockIdx.x, t = threadIdx.x;
    int rpb = 1 << shift;
    int r0 = b << shift;
    int rows = n - r0;
    if (rows <= 0) return;
    if (rows > rpb) rows = rpb;
    int ebase = bptr[b], eend = bptr[b + 1];
    for (int i = t; i < rows; i += 512) cnt[i] = 0;
    __syncthreads();
    for (int e = ebase + t; e < eend; e += 512) atomicAdd(&cnt[rcbin[e].x - r0], 1);
    __syncthreads();
    // exclusive scan of cnt[0..rows): 2 values per thread + block scan
    int v[2], s = 0;
#pragma unroll
    for (int j = 0; j < 2; j++) {
        int idx = t * 2 + j;
        v[j] = (idx < rows) ? cnt[idx] : 0;
        s += v[j];
    }
    red[t] = s;
    __syncthreads();
    for (int off = 1; off < 512; off <<= 1) {
        int u = (t >= off) ? red[t - off] : 0;
        __syncthreads();
        red[t] += u;
        __syncthreads();
    }
    int run = ebase + red[t] - s;
#pragma unroll
    for (int j = 0; j < 2; j++) {
        int idx = t * 2 + j;
        if (idx < rows) {
            row_ptr[r0 + idx] = run;
            curs[idx] = run;
            run += v[j];
        }
    }
    __syncthreads();
    for (int e = ebase + t; e < eend; e += 512) {
        int2 rc = rcbin[e];
        float vv = valbin[e];
        int pos = atomicAdd(&curs[rc.x - r0], 1);
        col_s[pos] = rc.y;
        val_s[pos] = vv;
    }
}

// ---------------- SpMM: ax = A @ x  (CSR, one wave per row) ----------------
// Round-9: REVERT to round-7 measured-best form (70us, occ 75%): one row per
// wave, 4-deep gather unroll (16 in flight). Round-8's 2-row variant regressed
// (80us, occ 55%) via row-length imbalance + doubled live state. Outputs are
// pre-split bf16 hi/lo planes.

__device__ __forceinline__ void store_split4(short* __restrict__ hi, short* __restrict__ lo,
                                             size_t o, const float4& v) {
    short4 h4, l4;
    split1(v.x, h4.x, l4.x); split1(v.y, h4.y, l4.y);
    split1(v.z, h4.z, l4.z); split1(v.w, h4.w, l4.w);
    *(short4*)(hi + o) = h4;
    *(short4*)(lo + o) = l4;
}

__global__ __launch_bounds__(256) void spmm_dual(const float* __restrict__ X,
                                                 const int* __restrict__ row_ptr,
                                                 const int* __restrict__ col_s,
                                                 const float* __restrict__ val_s,
                                                 const unsigned char* __restrict__ mask, int n,
                                                 short* __restrict__ axm_hi,
                                                 short* __restrict__ axm_lo,
                                                 short* __restrict__ axf_hi,
                                                 short* __restrict__ axf_lo) {
    int gid = blockIdx.x * 256 + threadIdx.x;
    int r = gid >> 6;
    if (r >= n) return;
    int lane = threadIdx.x & 63;
    int g = lane >> 4, sub = lane & 15;
    int s = row_ptr[r], e = row_ptr[r + 1];
    int cnt = e - s;
    int myc = 0;
    float myvf = 0.f, myvm = 0.f;
    if (lane < cnt) {
        myc = col_s[s + lane];
        float v = val_s[s + lane];
        myvf = v;
        myvm = mask[myc] ? 0.f : v;
    }
    int cmain = cnt > 64 ? 64 : cnt;
    float4 fA = {0, 0, 0, 0}, fB = {0, 0, 0, 0}, mA = {0, 0, 0, 0}, mB = {0, 0, 0, 0};
    for (int i = 0; i < cmain; i += 16) {
        int i0 = i + g, i1 = i + 4 + g, i2 = i + 8 + g, i3 = i + 12 + g;
        int c0 = __shfl(myc, i0), c1 = __shfl(myc, i1);
        int c2 = __shfl(myc, i2), c3 = __shfl(myc, i3);
        float vf0 = __shfl(myvf, i0), vf1 = __shfl(myvf, i1);
        float vf2 = __shfl(myvf, i2), vf3 = __shfl(myvf, i3);
        float vm0 = __shfl(myvm, i0), vm1 = __shfl(myvm, i1);
        float vm2 = __shfl(myvm, i2), vm3 = __shfl(myvm, i3);
        if (i0 < cmain) {
            float4 x = *(const float4*)(X + (size_t)c0 * 64 + sub * 4);
            fma4(fA, vf0, x);
            fma4(mA, vm0, x);
        }
        if (i1 < cmain) {
            float4 x = *(const float4*)(X + (size_t)c1 * 64 + sub * 4);
            fma4(fB, vf1, x);
            fma4(mB, vm1, x);
        }
        if (i2 < cmain) {
            float4 x = *(const float4*)(X + (size_t)c2 * 64 + sub * 4);
            fma4(fA, vf2, x);
            fma4(mA, vm2, x);
        }
        if (i3 < cmain) {
            float4 x = *(const float4*)(X + (size_t)c3 * 64 + sub * 4);
            fma4(fB, vf3, x);
            fma4(mB, vm3, x);
        }
    }
    for (int i = 64 + g; i < cnt; i += 4) {  // rare overflow rows
        int c = col_s[s + i];
        float v = val_s[s + i];
        float vm = mask[c] ? 0.f : v;
        float4 x = *(const float4*)(X + (size_t)c * 64 + sub * 4);
        fma4(fA, v, x);
        fma4(mA, vm, x);
    }
    fA.x += fB.x; fA.y += fB.y; fA.z += fB.z; fA.w += fB.w;
    mA.x += mB.x; mA.y += mB.y; mA.z += mB.z; mA.w += mB.w;
    red4(fA);
    red4(mA);
    if (g == 0) {
        size_t o = (size_t)r * 64 + sub * 4;
        store_split4(axf_hi, axf_lo, o, fA);
        store_split4(axm_hi, axm_lo, o, mA);
    }
}

// Single-output masked SpMM; masked edges skip the gather entirely.
__global__ __launch_bounds__(256) void spmm_one(const float* __restrict__ X,
                                                const int* __restrict__ row_ptr,
                                                const int* __restrict__ col_s,
                                                const float* __restrict__ val_s,
                                                const unsigned char* __restrict__ mask, int n,
                                                short* __restrict__ ax_hi,
                                                short* __restrict__ ax_lo) {
    int gid = blockIdx.x * 256 + threadIdx.x;
    int r = gid >> 6;
    if (r >= n) return;
    int lane = threadIdx.x & 63;
    int g = lane >> 4, sub = lane & 15;
    int s = row_ptr[r], e = row_ptr[r + 1];
    int cnt = e - s;
    int myc = 0;
    float myv = 0.f;
    if (lane < cnt) {
        myc = col_s[s + lane];
        float v = val_s[s + lane];
        myv = mask[myc] ? 0.f : v;
    }
    int cmain = cnt > 64 ? 64 : cnt;
    float4 aA = {0, 0, 0, 0}, aB = {0, 0, 0, 0};
    for (int i = 0; i < cmain; i += 16) {
        int i0 = i + g, i1 = i + 4 + g, i2 = i + 8 + g, i3 = i + 12 + g;
        int c0 = __shfl(myc, i0), c1 = __shfl(myc, i1);
        int c2 = __shfl(myc, i2), c3 = __shfl(myc, i3);
        float v0 = __shfl(myv, i0), v1 = __shfl(myv, i1);
        float v2 = __shfl(myv, i2), v3 = __shfl(myv, i3);
        if (i0 < cmain && v0 != 0.f) {
            float4 x = *(const float4*)(X + (size_t)c0 * 64 + sub * 4);
            fma4(aA, v0, x);
        }
        if (i1 < cmain && v1 != 0.f) {
            float4 x = *(const float4*)(X + (size_t)c1 * 64 + sub * 4);
            fma4(aB, v1, x);
        }
        if (i2 < cmain && v2 != 0.f) {
            float4 x = *(const float4*)(X + (size_t)c2 * 64 + sub * 4);
            fma4(aA, v2, x);
        }
        if (i3 < cmain && v3 != 0.f) {
            float4 x = *(const float4*)(X + (size_t)c3 * 64 + sub * 4);
            fma4(aB, v3, x);
        }
    }
    for (int i = 64 + g; i < cnt; i += 4) {
        int c = col_s[s + i];
        if (mask[c]) continue;
        float v = val_s[s + i];
        float4 x = *(const float4*)(X + (size_t)c * 64 + sub * 4);
        fma4(aA, v, x);
    }
    aA.x += aB.x; aA.y += aB.y; aA.z += aB.z; aA.w += aB.w;
    red4(aA);
    if (g == 0) {
        size_t o = (size_t)r * 64 + sub * 4;
        store_split4(ax_hi, ax_lo, o, aA);
    }
}

// ---------------- fused kernel A: embed GEMM -> LDS bf16 planes -> fc GEMM -> tanh-sum ----
// blockIdx.y selects plane-set {0,1} (merged pass0/pass1 tails); s_sums offset
// by set*512. A-fragments direct from pre-split global planes + prefetch.

template <int PP>
__global__ __launch_bounds__(256) void gemm_tanh(const short* __restrict__ Xhi0,
                                                 const short* __restrict__ Xlo0,
                                                 const short* __restrict__ Xhi1,
                                                 const short* __restrict__ Xlo1,
                                                 const float* __restrict__ Wg,
                                                 const float* __restrict__ b,
                                                 const float* __restrict__ a,
                                                 const float* __restrict__ fcw,
                                                 const float* __restrict__ fcb, int n, int ntiles,
                                                 float* __restrict__ s_sums) {
    __shared__ __align__(16) short ehi[PP][16][72], elo[PP][16][72];
    int set = blockIdx.y;
    const short* __restrict__ Xhi = set ? Xhi1 : Xhi0;
    const short* __restrict__ Xlo = set ? Xlo1 : Xlo0;
    float* __restrict__ ss = s_sums + set * 512;
    int t = threadIdx.x;
    int wv = t >> 6, lane = t & 63, nl = lane & 15, q = lane >> 4;
    int colg = wv * 16 + nl;
    bf16x8 whi[PP][2], wlo[PP][2];
    float bias[PP], slope[PP];
#pragma unroll
    for (int p = 0; p < PP; p++) {
#pragma unroll
        for (int kk = 0; kk < 2; kk++)
            split8(Wg + p * 4096 + colg * 64 + kk * 32 + q * 8, true, whi[p][kk], wlo[p][kk]);
        bias[p] = b[p * 64 + colg];
        slope[p] = a[p];
    }
    bf16x8 fhi[2], flo[2];
#pragma unroll
    for (int kk = 0; kk < 2; kk++)
        split8(fcw + colg * 64 + kk * 32 + q * 8, true, fhi[kk], flo[kk]);
    float fbias = fcb[colg];
    float ssum[PP];
#pragma unroll
    for (int p = 0; p < PP; p++) ssum[p] = 0.f;

    int rt = blockIdx.x;
    bf16x8 ah[2], al[2];
    if (rt < ntiles) {
        size_t rb = (size_t)(rt * 16 + nl) * 64 + q * 8;
#pragma unroll
        for (int kk = 0; kk < 2; kk++) {
            ah[kk] = *(const bf16x8*)(Xhi + rb + kk * 32);
            al[kk] = *(const bf16x8*)(Xlo + rb + kk * 32);
        }
    }
    for (; rt < ntiles; rt += gridDim.x) {
#pragma unroll
        for (int p = 0; p < PP; p++) {
            f32x4 acc = {0.f, 0.f, 0.f, 0.f};
            acc = __builtin_amdgcn_mfma_f32_16x16x32_bf16(ah[0], whi[p][0], acc, 0, 0, 0);
            acc = __builtin_amdgcn_mfma_f32_16x16x32_bf16(ah[1], whi[p][1], acc, 0, 0, 0);
            acc = __builtin_amdgcn_mfma_f32_16x16x32_bf16(al[0], whi[p][0], acc, 0, 0, 0);
            acc = __builtin_amdgcn_mfma_f32_16x16x32_bf16(al[1], whi[p][1], acc, 0, 0, 0);
            acc = __builtin_amdgcn_mfma_f32_16x16x32_bf16(ah[0], wlo[p][0], acc, 0, 0, 0);
            acc = __builtin_amdgcn_mfma_f32_16x16x32_bf16(ah[1], wlo[p][1], acc, 0, 0, 0);
            acc = __builtin_amdgcn_mfma_f32_16x16x32_bf16(al[0], wlo[p][0], acc, 0, 0, 0);
            acc = __builtin_amdgcn_mfma_f32_16x16x32_bf16(al[1], wlo[p][1], acc, 0, 0, 0);
#pragma unroll
            for (int i = 0; i < 4; i++) {
                float o = acc[i] + bias[p];
                o = (o > 0.f) ? o : slope[p] * o;
                short hb, lb;
                split1(o, hb, lb);
                ehi[p][q * 4 + i][colg] = hb;
                elo[p][q * 4 + i][colg] = lb;
            }
        }
        // prefetch next tile's A-fragments (overlaps the fc phase below)
        int rn = rt + gridDim.x;
        bf16x8 pfh[2], pfl[2];
        if (rn < ntiles) {
            size_t rb = (size_t)(rn * 16 + nl) * 64 + q * 8;
#pragma unroll
            for (int kk = 0; kk < 2; kk++) {
                pfh[kk] = *(const bf16x8*)(Xhi + rb + kk * 32);
                pfl[kk] = *(const bf16x8*)(Xlo + rb + kk * 32);
            }
        }
        __syncthreads();
#pragma unroll
        for (int p = 0; p < PP; p++) {
            bf16x8 eh[2], el[2];
#pragma unroll
            for (int kk = 0; kk < 2; kk++) {
                eh[kk] = *(const bf16x8*)(&ehi[p][nl][kk * 32 + q * 8]);
                el[kk] = *(const bf16x8*)(&elo[p][nl][kk * 32 + q * 8]);
            }
            f32x4 acc = {0.f, 0.f, 0.f, 0.f};
            acc = __builtin_amdgcn_mfma_f32_16x16x32_bf16(eh[0], fhi[0], acc, 0, 0, 0);
            acc = __builtin_amdgcn_mfma_f32_16x16x32_bf16(eh[1], fhi[1], acc, 0, 0, 0);
            acc = __builtin_amdgcn_mfma_f32_16x16x32_bf16(el[0], fhi[0], acc, 0, 0, 0);
            acc = __builtin_amdgcn_mfma_f32_16x16x32_bf16(el[1], fhi[1], acc, 0, 0, 0);
            acc = __builtin_amdgcn_mfma_f32_16x16x32_bf16(eh[0], flo[0], acc, 0, 0, 0);
            acc = __builtin_amdgcn_mfma_f32_16x16x32_bf16(eh[1], flo[1], acc, 0, 0, 0);
#pragma unroll
            for (int i = 0; i < 4; i++) {
                int r = rt * 16 + q * 4 + i;
                if (r < n) ssum[p] += fast_tanh(acc[i] + fbias);
            }
        }
        __syncthreads();  // LDS reads done before next tile's writes
#pragma unroll
        for (int kk = 0; kk < 2; kk++) {
            ah[kk] = pfh[kk];
            al[kk] = pfl[kk];
        }
    }
#pragma unroll
    for (int p = 0; p < PP; p++) {
        float s = ssum[p];
        s += __shfl_xor(s, 16);
        s += __shfl_xor(s, 32);
        if (q == 0) atomicAdd(&ss[p * 64 + colg], s);
    }
}

// ---------------- fused kernel B: recompute embed GEMM, mix with beta, write out -----------
// blockIdx.y selects plane-set + beta set + output slice.

template <int PP>
__global__ __launch_bounds__(256) void gemm_mix(const short* __restrict__ Xhi0,
                                                const short* __restrict__ Xlo0,
                                                const short* __restrict__ Xhi1,
                                                const short* __restrict__ Xlo1,
                                                const float* __restrict__ Wg,
                                                const float* __restrict__ b,
                                                const float* __restrict__ a,
                                                const float* __restrict__ beta, int n, int ntiles,
                                                float* __restrict__ outbase, int accum) {
    int set = blockIdx.y;
    const short* __restrict__ Xhi = set ? Xhi1 : Xhi0;
    const short* __restrict__ Xlo = set ? Xlo1 : Xlo0;
    float* __restrict__ out = outbase + (size_t)set * n * 64;
    int t = threadIdx.x;
    int wv = t >> 6, lane = t & 63, nl = lane & 15, q = lane >> 4;
    int colg = wv * 16 + nl;
    bf16x8 whi[PP][2], wlo[PP][2];
    float bias[PP], slope[PP], bet[PP];
#pragma unroll
    for (int p = 0; p < PP; p++) {
#pragma unroll
        for (int kk = 0; kk < 2; kk++)
            split8(Wg + p * 4096 + colg * 64 + kk * 32 + q * 8, true, whi[p][kk], wlo[p][kk]);
        bias[p] = b[p * 64 + colg];
        slope[p] = a[p];
        bet[p] = beta[set * 8 + p];
    }
    int rt = blockIdx.x;
    bf16x8 ah[2], al[2];
    if (rt < ntiles) {
        size_t rb = (size_t)(rt * 16 + nl) * 64 + q * 8;
#pragma unroll
        for (int kk = 0; kk < 2; kk++) {
            ah[kk] = *(const bf16x8*)(Xhi + rb + kk * 32);
            al[kk] = *(const bf16x8*)(Xlo + rb + kk * 32);
        }
    }
    for (; rt < ntiles; rt += gridDim.x) {
        int rn = rt + gridDim.x;
        bf16x8 pfh[2], pfl[2];
        if (rn < ntiles) {
            size_t rb = (size_t)(rn * 16 + nl) * 64 + q * 8;
#pragma unroll
            for (int kk = 0; kk < 2; kk++) {
                pfh[kk] = *(const bf16x8*)(Xhi + rb + kk * 32);
                pfl[kk] = *(const bf16x8*)(Xlo + rb + kk * 32);
            }
        }
        float mix[4] = {0.f, 0.f, 0.f, 0.f};
#pragma unroll
        for (int p = 0; p < PP; p++) {
            f32x4 acc = {0.f, 0.f, 0.f, 0.f};
            acc = __builtin_amdgcn_mfma_f32_16x16x32_bf16(ah[0], whi[p][0], acc, 0, 0, 0);
            acc = __builtin_amdgcn_mfma_f32_16x16x32_bf16(ah[1], whi[p][1], acc, 0, 0, 0);
            acc = __builtin_amdgcn_mfma_f32_16x16x32_bf16(al[0], whi[p][0], acc, 0, 0, 0);
            acc = __builtin_amdgcn_mfma_f32_16x16x32_bf16(al[1], whi[p][1], acc, 0, 0, 0);
            acc = __builtin_amdgcn_mfma_f32_16x16x32_bf16(ah[0], wlo[p][0], acc, 0, 0, 0);
            acc = __builtin_amdgcn_mfma_f32_16x16x32_bf16(ah[1], wlo[p][1], acc, 0, 0, 0);
            acc = __builtin_amdgcn_mfma_f32_16x16x32_bf16(al[0], wlo[p][0], acc, 0, 0, 0);
            acc = __builtin_amdgcn_mfma_f32_16x16x32_bf16(al[1], wlo[p][1], acc, 0, 0, 0);
#pragma unroll
            for (int i = 0; i < 4; i++) {
                float o = acc[i] + bias[p];
                o = (o > 0.f) ? o : slope[p] * o;
                mix[i] = fmaf(bet[p], o, mix[i]);
            }
        }
#pragma unroll
        for (int i = 0; i < 4; i++) {
            int r = rt * 16 + q * 4 + i;
            if (r < n) {
                size_t idx = (size_t)r * 64 + colg;
                out[idx] = accum ? (out[idx] + mix[i]) : mix[i];
            }
        }
#pragma unroll
        for (int kk = 0; kk < 2; kk++) {
            ah[kk] = pfh[kk];
            al[kk] = pfl[kk];
        }
    }
}

// beta for nsets plane-sets in one 1-block launch.
__global__ __launch_bounds__(64) void compute_beta(const float* __restrict__ s_sums,
                                                   const float* __restrict__ att, int n, int P,
                                                   int nsets, float* __restrict__ beta) {
    int lane = threadIdx.x;
    float av = att[lane];
    for (int st = 0; st < nsets; st++) {
        const float* ss = s_sums + st * 512;
        float l[8];
        for (int p = 0; p < P; p++) l[p] = ss[p * 64 + lane] * av;
#pragma unroll
        for (int off = 32; off > 0; off >>= 1)
            for (int p = 0; p < 8; p++)
                if (p < P) l[p] += __shfl_down(l[p], off);
        if (lane == 0) {
            const float inv = 1.0f / (float)n;
            float m = -1e30f;
            for (int p = 0; p < P; p++) {
                l[p] *= inv;
                m = fmaxf(m, l[p]);
            }
            float s = 0.f;
            for (int p = 0; p < P; p++) {
                l[p] = __expf(l[p] - m);
                s += l[p];
            }
            for (int p = 0; p < P; p++) beta[st * 8 + p] = l[p] / s;
        }
    }
}

// ---------------- driver ----------------

extern "C" void kernel_launch(void* const* d_in, const int* in_sizes, int n_in,
                              void* d_out, int out_size, void* d_ws, size_t ws_size,
                              hipStream_t stream) {
    const float* h = (const float*)d_in[0];
    const float* W = (const float*)d_in[1];
    const float* b = (const float*)d_in[2];
    const float* a = (const float*)d_in[3];
    const float* fc_w = (const float*)d_in[4];
    const float* fc_b = (const float*)d_in[5];
    const float* att = (const float*)d_in[6];
    const float* adj = (const float*)d_in[7];
    const void* row = d_in[8];
    const void* col = d_in[9];
    const void* mask1 = d_in[10];
    const void* mask2 = d_in[11];
    float* out = (float*)d_out;

    int P = in_sizes[3];
    if (P < 1 || P > 8) P = 3;
    int N = in_sizes[0] / 64;
    int E = in_sizes[7];
    int N16 = (N + 15) & ~15;
    int ntiles = N16 >> 4;

    // bucket geometry: rows/bucket = 1<<shift, buckets <= 2048
    int shift = 8;
    while (((N >> shift) + 1) > 2048) shift++;
    int NB = (N >> shift) + 1;

    char* w = (char*)d_ws;
    auto alloc = [&](size_t bytes) {
        void* p = (void*)w;
        w += (bytes + 255) & ~(size_t)255;
        return p;
    };
    int* row_ptr = (int*)alloc((size_t)(N + 1) * 4);
    int* col_s = (int*)alloc((size_t)E * 4);
    float* val_s = (float*)alloc((size_t)E * 4);
    int* bptr = (int*)alloc((size_t)(NB + 1) * 4);
    int* bcur = (int*)alloc((size_t)NB * 4);
    int2* rcbin = (int2*)alloc((size_t)E * 8);
    float* valbin = (float*)alloc((size_t)E * 4);
    unsigned char* m1c = (unsigned char*)alloc(N);
    unsigned char* m2c = (unsigned char*)alloc(N);
    short* axm_hi = (short*)alloc((size_t)N16 * 64 * 2);
    short* axm_lo = (short*)alloc((size_t)N16 * 64 * 2);
    short* axf_hi = (short*)alloc((size_t)N16 * 64 * 2);
    short* axf_lo = (short*)alloc((size_t)N16 * 64 * 2);
    float* s_sums = (float*)alloc(2 * 512 * 4);
    float* beta = (float*)alloc(64 * 4);
    int* flags = (int*)alloc(256);

    int nw_mask = N / 4 > 25000 ? 25000 : N / 4;
    int nw_idx = E / 4 > 25000 ? 25000 : E / 4;
    forensic_kernel<<<1, 256, 0, stream>>>((const unsigned int*)mask1, (const unsigned int*)row,
                                           nw_mask, nw_idx, flags);
    conv_masks<<<(N + 255) / 256, 256, 0, stream>>>(mask1, mask2, flags, N, m1c, m2c);

    hipMemsetAsync(bptr, 0, (size_t)(NB + 1) * 4, stream);
    if (N16 > N) {  // zero pad rows so tail-tile fragment loads need no predicate
        size_t padoff = (size_t)N * 64, padbytes = (size_t)(N16 - N) * 64 * 2;
        hipMemsetAsync(axm_hi + padoff, 0, padbytes, stream);
        hipMemsetAsync(axm_lo + padoff, 0, padbytes, stream);
        hipMemsetAsync(axf_hi + padoff, 0, padbytes, stream);
        hipMemsetAsync(axf_lo + padoff, 0, padbytes, stream);
    }
    bucket_hist<<<1024, 256, 0, stream>>>(row, flags, E, N, shift, NB, bptr);
    bucket_scan<<<1, 1024, 0, stream>>>(bptr, NB, bcur, N, row_ptr);
    int bin_blocks = (E + 2047) / 2048;
    bin_pass2<<<bin_blocks, 256, 0, stream>>>(row, col, adj, flags, E, N, shift, NB, bcur, rcbin,
                                              valbin);
    csr_finalize<<<NB, 512, 0, stream>>>(bptr, rcbin, valbin, N, shift, row_ptr, col_s, val_s);

    int spmm_grid = (int)(((size_t)N * 64 + 255) / 256);  // one wave per row
    int tanh_blocks = 1024;
    int mix_blocks = 1024;

    auto tail = [&](const short* xh0, const short* xl0, const short* xh1, const short* xl1,
                    int nsets, float* dst) {
        hipMemsetAsync(s_sums, 0, 2 * 512 * 4, stream);
        if (P == 3) {
            gemm_tanh<3><<<dim3(tanh_blocks, nsets), 256, 0, stream>>>(
                xh0, xl0, xh1, xl1, W, b, a, fc_w, fc_b, N, ntiles, s_sums);
        } else {
            for (int p = 0; p < P; p++)
                gemm_tanh<1><<<dim3(tanh_blocks, nsets), 256, 0, stream>>>(
                    xh0, xl0, xh1, xl1, W + p * 4096, b + p * 64, a + p, fc_w, fc_b, N, ntiles,
                    s_sums + p * 64);
        }
        compute_beta<<<1, 64, 0, stream>>>(s_sums, att, N, P, nsets, beta);
        if (P == 3) {
            gemm_mix<3><<<dim3(mix_blocks, nsets), 256, 0, stream>>>(
                xh0, xl0, xh1, xl1, W, b, a, beta, N, ntiles, dst, 0);
        } else {
            for (int p = 0; p < P; p++)
                gemm_mix<1><<<dim3(mix_blocks, nsets), 256, 0, stream>>>(
                    xh0, xl0, xh1, xl1, W + p * 4096, b + p * 64, a + p, beta + p, N, ntiles, dst,
                    p != 0);
        }
    };

    // passes 0+1: one edge sweep -> {axm, axf}; merged tails (gridDim.y = 2)
    spmm_dual<<<spmm_grid, 256, 0, stream>>>(h, row_ptr, col_s, val_s, m1c, N, axm_hi, axm_lo,
                                             axf_hi, axf_lo);
    tail(axm_hi, axm_lo, axf_hi, axf_lo, 2, out);  // z_mp, z_mp2
    // pass 2 decodes from z_mp (in d_out), masked by mask2
    spmm_one<<<spmm_grid, 256, 0, stream>>>(out, row_ptr, col_s, val_s, m2c, N, axm_hi, axm_lo);
    tail(axm_hi, axm_lo, axm_hi, axm_lo, 1, out + (size_t)2 * N * 64);  // x_recon
}